// Round 1
// baseline (1215.157 us; speedup 1.0000x reference)
//
#include <hip/hip_runtime.h>

// Problem constants (from setup_inputs)
#define NU 50000
#define NM 50000
#define NN 100000   // NU + NM
#define FU 32
#define FM 64
#define HD 128
#define NC 10

// ---------------- CSR build ----------------

__global__ void k_count(const int* __restrict__ col, int E, int* __restrict__ counts) {
    int e = blockIdx.x * blockDim.x + threadIdx.x;
    if (e < E) atomicAdd(&counts[col[e]], 1);
}

__global__ void k_dinv(const int* __restrict__ counts, float* __restrict__ dinv) {
    int i = blockIdx.x * blockDim.x + threadIdx.x;
    if (i < NN) dinv[i] = rsqrtf((float)(counts[i] + 1));  // +1 self loop
}

// Single-block exclusive scan over NN counts -> offsets[NN+1]; cursor = copy.
__global__ void k_scan(const int* __restrict__ counts, int* __restrict__ offsets,
                       int* __restrict__ cursor) {
    __shared__ int part[1024];
    const int n = NN;
    int t = threadIdx.x;
    int chunk = (n + 1023) / 1024;
    int b = t * chunk;
    int e = min(b + chunk, n);
    int s = 0;
    for (int i = b; i < e; i++) s += counts[i];
    part[t] = s;
    __syncthreads();
    for (int off = 1; off < 1024; off <<= 1) {
        int v = (t >= off) ? part[t - off] : 0;
        __syncthreads();
        part[t] += v;
        __syncthreads();
    }
    int run = (t == 0) ? 0 : part[t - 1];
    for (int i = b; i < e; i++) {
        offsets[i] = run;
        cursor[i] = run;
        run += counts[i];
    }
    if (t == 1023) offsets[n] = run;  // == E
}

__global__ void k_fill(const int* __restrict__ row, const int* __restrict__ col, int E,
                       int* __restrict__ cursor, int* __restrict__ csr_src) {
    int e = blockIdx.x * blockDim.x + threadIdx.x;
    if (e < E) {
        int c = col[e];
        int pos = atomicAdd(&cursor[c], 1);
        csr_src[pos] = row[e];
    }
}

// ---------------- dense transforms ----------------

// x_user @ Wu^T + bu  (rows 0..NU) ; x_movie @ Wm^T + bm (rows NU..NN) -> out[NN][HD]
__global__ void k_embed(const float* __restrict__ xu, const float* __restrict__ xm,
                        const float* __restrict__ Wu, const float* __restrict__ bu,
                        const float* __restrict__ Wm, const float* __restrict__ bm,
                        float* __restrict__ out) {
    int n = blockIdx.x;
    int t = threadIdx.x;  // 128 threads, one output channel each
    __shared__ float xs[FM];
    if (n < NU) {
        if (t < FU) xs[t] = xu[(size_t)n * FU + t];
        __syncthreads();
        float acc = bu[t];
#pragma unroll
        for (int i = 0; i < FU; i++) acc += xs[i] * Wu[t * FU + i];
        out[(size_t)n * HD + t] = acc;
    } else {
        int m = n - NU;
        if (t < FM) xs[t] = xm[(size_t)m * FM + t];
        __syncthreads();
        float acc = bm[t];
#pragma unroll
        for (int i = 0; i < FM; i++) acc += xs[i] * Wm[t * FM + i];
        out[(size_t)n * HD + t] = acc;
    }
}

// out[n] = (RELU? relu(x[n]) : x[n]) @ W^T + b ;  W is [HD][HD]
template <bool RELU>
__global__ void k_gemm(const float* __restrict__ x, const float* __restrict__ W,
                       const float* __restrict__ b, float* __restrict__ out) {
    constexpr int MB = 8;  // nodes per block
    __shared__ float xs[MB][HD];
    int n0 = blockIdx.x * MB;
    int t = threadIdx.x;  // 128
#pragma unroll
    for (int m = 0; m < MB; m++) {
        float v = x[(size_t)(n0 + m) * HD + t];
        xs[m][t] = RELU ? fmaxf(v, 0.f) : v;
    }
    __syncthreads();
    float acc[MB];
    float bv = b[t];
#pragma unroll
    for (int m = 0; m < MB; m++) acc[m] = bv;
    const float4* Wr = (const float4*)&W[t * HD];
#pragma unroll 8
    for (int k4 = 0; k4 < HD / 4; k4++) {
        float4 w = Wr[k4];
#pragma unroll
        for (int m = 0; m < MB; m++) {
            acc[m] += xs[m][4 * k4 + 0] * w.x;
            acc[m] += xs[m][4 * k4 + 1] * w.y;
            acc[m] += xs[m][4 * k4 + 2] * w.z;
            acc[m] += xs[m][4 * k4 + 3] * w.w;
        }
    }
#pragma unroll
    for (int m = 0; m < MB; m++) out[(size_t)(n0 + m) * HD + t] = acc[m];
}

// out[c] = dinv[c]^2 * h[c] + sum_{r in nbr(c)} dinv[c]*dinv[r]*h[r]
__global__ void k_agg(const float* __restrict__ h, const int* __restrict__ offsets,
                      const int* __restrict__ csr_src, const float* __restrict__ dinv,
                      float* __restrict__ out) {
    int n = blockIdx.x;
    int t = threadIdx.x;  // 128
    float dn = dinv[n];
    float acc = dn * dn * h[(size_t)n * HD + t];
    int s = offsets[n], e = offsets[n + 1];
    for (int j = s; j < e; j++) {
        int r = csr_src[j];
        acc += dn * dinv[r] * h[(size_t)r * HD + t];
    }
    out[(size_t)n * HD + t] = acc;
}

// P[n][j] = We[j, half(n)] . relu(x2[n]) (+ be[j] if user node)
__global__ void k_proj(const float* __restrict__ x2, const float* __restrict__ We,
                       const float* __restrict__ be, float* __restrict__ P) {
    int n = blockIdx.x;
    int l = threadIdx.x;  // 64 lanes
    const float* xr = &x2[(size_t)n * HD];
    float v0 = fmaxf(xr[l], 0.f);
    float v1 = fmaxf(xr[l + 64], 0.f);
    int off = (n < NU) ? 0 : HD;
    float p[NC];
#pragma unroll
    for (int j = 0; j < NC; j++) {
        const float* wr = &We[j * (2 * HD) + off];
        p[j] = wr[l] * v0 + wr[l + 64] * v1;
    }
#pragma unroll
    for (int j = 0; j < NC; j++) {
#pragma unroll
        for (int m = 32; m >= 1; m >>= 1) p[j] += __shfl_xor(p[j], m, 64);
    }
    if (l == 0) {
        bool user = (n < NU);
#pragma unroll
        for (int j = 0; j < NC; j++) P[(size_t)n * NC + j] = p[j] + (user ? be[j] : 0.f);
    }
}

// out[e] = P[row[e]] + P[NU + col[e]]
__global__ void k_edge_out(const int* __restrict__ row, const int* __restrict__ col,
                           const float* __restrict__ P, float* __restrict__ out, int E) {
    int e = blockIdx.x * blockDim.x + threadIdx.x;
    if (e < E) {
        int r = row[e];
        int c = col[e];
        const float* pu = &P[(size_t)r * NC];
        const float* pm = &P[(size_t)(NU + c) * NC];
        float* o = &out[(size_t)e * NC];
#pragma unroll
        for (int j = 0; j < NC; j++) o[j] = pu[j] + pm[j];
    }
}

extern "C" void kernel_launch(void* const* d_in, const int* in_sizes, int n_in,
                              void* d_out, int out_size, void* d_ws, size_t ws_size,
                              hipStream_t stream) {
    const float* x_user  = (const float*)d_in[0];
    const float* x_movie = (const float*)d_in[1];
    const int*   ei      = (const int*)d_in[2];
    const float* Wu = (const float*)d_in[3];
    const float* bu = (const float*)d_in[4];
    const float* Wm = (const float*)d_in[5];
    const float* bm = (const float*)d_in[6];
    const float* W1 = (const float*)d_in[7];
    const float* b1 = (const float*)d_in[8];
    const float* W2 = (const float*)d_in[9];
    const float* b2 = (const float*)d_in[10];
    const float* We = (const float*)d_in[11];
    const float* be = (const float*)d_in[12];
    float* out = (float*)d_out;

    int E = in_sizes[2] / 2;
    const int* row = ei;
    const int* col = ei + E;

    // workspace carve-up (256B aligned)
    char* p = (char*)d_ws;
    auto alloc = [&](size_t bytes) -> void* {
        void* r = (void*)p;
        p += (bytes + 255) & ~(size_t)255;
        return r;
    };
    int*   counts  = (int*)alloc((size_t)NN * 4);
    int*   offsets = (int*)alloc((size_t)(NN + 1) * 4);
    int*   cursor  = (int*)alloc((size_t)NN * 4);
    int*   csr     = (int*)alloc((size_t)E * 4);
    float* dinv    = (float*)alloc((size_t)NN * 4);
    float* P       = (float*)alloc((size_t)NN * NC * 4);
    float* buf0    = (float*)alloc((size_t)NN * HD * 4);
    float* buf1    = (float*)alloc((size_t)NN * HD * 4);

    const int tb = 256;

    hipMemsetAsync(counts, 0, (size_t)NN * 4, stream);
    k_count<<<(E + tb - 1) / tb, tb, 0, stream>>>(col, E, counts);
    k_dinv<<<(NN + tb - 1) / tb, tb, 0, stream>>>(counts, dinv);
    k_scan<<<1, 1024, 0, stream>>>(counts, offsets, cursor);
    k_fill<<<(E + tb - 1) / tb, tb, 0, stream>>>(row, col, E, cursor, csr);

    k_embed<<<NN, 128, 0, stream>>>(x_user, x_movie, Wu, bu, Wm, bm, buf0);

    k_gemm<false><<<NN / 8, 128, 0, stream>>>(buf0, W1, b1, buf1);
    k_agg<<<NN, 128, 0, stream>>>(buf1, offsets, csr, dinv, buf0);

    k_gemm<true><<<NN / 8, 128, 0, stream>>>(buf0, W2, b2, buf1);
    k_agg<<<NN, 128, 0, stream>>>(buf1, offsets, csr, dinv, buf0);

    k_proj<<<NN, 64, 0, stream>>>(buf0, We, be, P);
    k_edge_out<<<(E + tb - 1) / tb, tb, 0, stream>>>(row, col, P, out, E);
}

// Round 2
// 564.929 us; speedup vs baseline: 2.1510x; 2.1510x over previous
//
#include <hip/hip_runtime.h>

#define NU 50000
#define NM 50000
#define NN 100000
#define FU 32
#define FM 64
#define HD 128
#define NC 10

// ---------------- CSR build ----------------

__global__ void k_count(const int* __restrict__ col, int E, int* __restrict__ counts) {
    int e = blockIdx.x * blockDim.x + threadIdx.x;
    if (e < E) atomicAdd(&counts[col[e]], 1);
}

__device__ inline int wave_incl_scan(int x, int l) {
#pragma unroll
    for (int d = 1; d < 64; d <<= 1) {
        int u = __shfl_up(x, d, 64);
        if (l >= d) x += u;
    }
    return x;
}

// block-wide exclusive scan; returns excl prefix; total via wsum
template <int NWAVE>
__device__ inline int block_excl_scan(int v, int t, int* wsum, int* out_total) {
    int l = t & 63, w = t >> 6;
    int inc = wave_incl_scan(v, l);
    if (l == 63) wsum[w] = inc;
    __syncthreads();
    int base = 0;
#pragma unroll
    for (int i = 0; i < NWAVE; i++) {
        int s = wsum[i];
        if (i < w) base += s;
        if (out_total) *out_total = (i == 0) ? s : (*out_total + s);
    }
    return base + inc - v;
}

// per-block sums of counts (256/block)
__global__ void k_scanA(const int* __restrict__ counts, int* __restrict__ sums) {
    __shared__ int wsum[4];
    int t = threadIdx.x;
    int idx = blockIdx.x * 256 + t;
    int v = (idx < NN) ? counts[idx] : 0;
    int total;
    block_excl_scan<4>(v, t, wsum, &total);
    if (t == 0) sums[blockIdx.x] = total;
}

// scan the 391 block sums in place; also offsets[NN] = E
__global__ void k_scanB(int* __restrict__ sums, int nblk, int* __restrict__ offsets) {
    __shared__ int wsum[8];
    int t = threadIdx.x;  // 512
    int v = (t < nblk) ? sums[t] : 0;
    int total;
    int excl = block_excl_scan<8>(v, t, wsum, &total);
    if (t < nblk) sums[t] = excl;
    if (t == 0) offsets[NN] = total;
}

// write offsets/cursor/dinv
__global__ void k_scanC(const int* __restrict__ counts, const int* __restrict__ sums,
                        int* __restrict__ offsets, int* __restrict__ cursor,
                        float* __restrict__ dinv) {
    __shared__ int wsum[4];
    int t = threadIdx.x;
    int idx = blockIdx.x * 256 + t;
    int v = (idx < NN) ? counts[idx] : 0;
    int excl = block_excl_scan<4>(v, t, wsum, nullptr);
    if (idx < NN) {
        int off = sums[blockIdx.x] + excl;
        offsets[idx] = off;
        cursor[idx] = off;
        dinv[idx] = rsqrtf((float)(v + 1));
    }
}

__global__ void k_fill(const int* __restrict__ row, const int* __restrict__ col, int E,
                       int* __restrict__ cursor, int* __restrict__ csr_src) {
    int e = blockIdx.x * blockDim.x + threadIdx.x;
    if (e < E) {
        int c = col[e];
        int pos = atomicAdd(&cursor[c], 1);
        csr_src[pos] = row[e];
    }
}

// ---------------- weight transpose (once) ----------------
// Wu 128x32 -> blocks [0,16); Wm 128x64 -> [16,48); W1 128x128 -> [48,112); W2 -> [112,176)
__global__ void k_transpose4(const float* __restrict__ Wu, const float* __restrict__ Wm,
                             const float* __restrict__ W1, const float* __restrict__ W2,
                             float* __restrict__ WuT, float* __restrict__ WmT,
                             float* __restrict__ W1T, float* __restrict__ W2T) {
    int bid = blockIdx.x;
    const float* src;
    float* dst;
    int kb, f0;
    if (bid < 16) { src = Wu; dst = WuT; kb = 5; f0 = bid * 256; }
    else if (bid < 48) { src = Wm; dst = WmT; kb = 6; f0 = (bid - 16) * 256; }
    else if (bid < 112) { src = W1; dst = W1T; kb = 7; f0 = (bid - 48) * 256; }
    else { src = W2; dst = W2T; kb = 7; f0 = (bid - 112) * 256; }
    int f = f0 + threadIdx.x;
    int c = f >> kb, k = f & ((1 << kb) - 1);
    dst[k * 128 + c] = src[f];
}

// ---------------- tiled GEMM: out[n][128] = scale * (act(x)[n][K] @ Wt + b) ----------------
// Wt is [K][128] (pre-transposed). PS: multiply row by dinv[n] (pre-scale for aggregation).
template <int K, bool RELU, bool PS>
__global__ void k_gemm(const float* __restrict__ x, const float* __restrict__ Wt,
                       const float* __restrict__ b, const float* __restrict__ dinvp,
                       float* __restrict__ out, int nrows) {
    __shared__ float xs[64 * K];
    int t = threadIdx.x;
    int n0 = blockIdx.x * 64;
    constexpr int F4R = K / 4;
    const float4* xv = (const float4*)x;
    float4* xsv = (float4*)xs;
#pragma unroll
    for (int i = t; i < 64 * F4R; i += 256) {
        int r = i / F4R;
        int n = n0 + r;
        float4 v = make_float4(0.f, 0.f, 0.f, 0.f);
        if (n < nrows) v = xv[(size_t)n * F4R + (i - r * F4R)];
        if (RELU) {
            v.x = fmaxf(v.x, 0.f); v.y = fmaxf(v.y, 0.f);
            v.z = fmaxf(v.z, 0.f); v.w = fmaxf(v.w, 0.f);
        }
        xsv[i] = v;
    }
    __syncthreads();

    int cg = t & 31;       // channel group: channels cg*4..cg*4+3
    int m0 = (t >> 5) * 8; // 8 nodes
    float4 bv = ((const float4*)b)[cg];
    float acc[8][4];
#pragma unroll
    for (int m = 0; m < 8; m++) {
        acc[m][0] = bv.x; acc[m][1] = bv.y; acc[m][2] = bv.z; acc[m][3] = bv.w;
    }
    const float4* Wt4 = (const float4*)Wt;
#pragma unroll 2
    for (int k4 = 0; k4 < K / 4; k4++) {
        int kb = k4 * 4;
        float4 w0 = Wt4[(kb + 0) * 32 + cg];
        float4 w1 = Wt4[(kb + 1) * 32 + cg];
        float4 w2 = Wt4[(kb + 2) * 32 + cg];
        float4 w3 = Wt4[(kb + 3) * 32 + cg];
#pragma unroll
        for (int m = 0; m < 8; m++) {
            float4 xf = *(const float4*)&xs[(m0 + m) * K + kb];
            acc[m][0] += xf.x * w0.x; acc[m][1] += xf.x * w0.y; acc[m][2] += xf.x * w0.z; acc[m][3] += xf.x * w0.w;
            acc[m][0] += xf.y * w1.x; acc[m][1] += xf.y * w1.y; acc[m][2] += xf.y * w1.z; acc[m][3] += xf.y * w1.w;
            acc[m][0] += xf.z * w2.x; acc[m][1] += xf.z * w2.y; acc[m][2] += xf.z * w2.z; acc[m][3] += xf.z * w2.w;
            acc[m][0] += xf.w * w3.x; acc[m][1] += xf.w * w3.y; acc[m][2] += xf.w * w3.z; acc[m][3] += xf.w * w3.w;
        }
    }
#pragma unroll
    for (int m = 0; m < 8; m++) {
        int n = n0 + m0 + m;
        if (n < nrows) {
            float s = PS ? dinvp[n] : 1.0f;
            float4 o = make_float4(acc[m][0] * s, acc[m][1] * s, acc[m][2] * s, acc[m][3] * s);
            ((float4*)out)[(size_t)n * 32 + cg] = o;
        }
    }
}

// ---------------- aggregation: wave per node, float2 per lane ----------------
// hp is pre-scaled by dinv. out[n] = dinv[n] * (hp[n] + sum_{r in nbr} hp[r])
// EPI: instead of storing the row, compute P[n][0..9] = We[:, half] . relu(row) (+be for users)
template <bool EPI>
__global__ void k_agg(const float* __restrict__ hp, const int* __restrict__ offsets,
                      const int* __restrict__ csr, const float* __restrict__ dinv,
                      float* __restrict__ out, const float* __restrict__ We,
                      const float* __restrict__ be, float* __restrict__ P) {
    int t = threadIdx.x;
    int l = t & 63, w = t >> 6;
    int n = blockIdx.x * 4 + w;
    const float2* hv = (const float2*)hp;
    float2 acc = hv[(size_t)n * 64 + l];
    int s = offsets[n], e = offsets[n + 1];
    int j = s;
    for (; j + 4 <= e; j += 4) {
        int r0 = csr[j], r1 = csr[j + 1], r2 = csr[j + 2], r3 = csr[j + 3];
        float2 a = hv[(size_t)r0 * 64 + l];
        float2 b2 = hv[(size_t)r1 * 64 + l];
        float2 c = hv[(size_t)r2 * 64 + l];
        float2 d = hv[(size_t)r3 * 64 + l];
        acc.x += a.x + b2.x + c.x + d.x;
        acc.y += a.y + b2.y + c.y + d.y;
    }
    for (; j < e; j++) {
        int r = csr[j];
        float2 v = hv[(size_t)r * 64 + l];
        acc.x += v.x; acc.y += v.y;
    }
    float dn = dinv[n];
    acc.x *= dn; acc.y *= dn;
    if (!EPI) {
        ((float2*)out)[(size_t)n * 64 + l] = acc;
    } else {
        float v0 = fmaxf(acc.x, 0.f), v1 = fmaxf(acc.y, 0.f);
        bool user = (n < NU);
        int off = user ? 0 : HD;
        float p[NC];
#pragma unroll
        for (int q = 0; q < NC; q++) {
            float2 wv = *(const float2*)&We[q * (2 * HD) + off + 2 * l];
            p[q] = wv.x * v0 + wv.y * v1;
        }
#pragma unroll
        for (int q = 0; q < NC; q++) {
#pragma unroll
            for (int d = 32; d >= 1; d >>= 1) p[q] += __shfl_xor(p[q], d, 64);
        }
        if (l == 0) {
#pragma unroll
            for (int q = 0; q < NC; q++) P[(size_t)n * NC + q] = p[q] + (user ? be[q] : 0.f);
        }
    }
}

// ---------------- edge output: out[e] = P[row[e]] + P[NU+col[e]] ----------------
__global__ void k_edge_out(const int* __restrict__ row, const int* __restrict__ col,
                           const float* __restrict__ P, float* __restrict__ out, int E) {
    __shared__ float ls[256 * 11];
    int t = threadIdx.x;
    int e0 = blockIdx.x * 256;
    int e = e0 + t;
    if (e < E) {
        int r = row[e], c = col[e];
        const float2* pu = (const float2*)(P + (size_t)r * NC);
        const float2* pm = (const float2*)(P + (size_t)(NU + c) * NC);
#pragma unroll
        for (int q = 0; q < 5; q++) {
            float2 a = pu[q], b = pm[q];
            ls[t * 11 + 2 * q] = a.x + b.x;
            ls[t * 11 + 2 * q + 1] = a.y + b.y;
        }
    }
    __syncthreads();
    int nvals = (E - e0 < 256 ? E - e0 : 256) * NC;
    size_t base = (size_t)e0 * NC;
    for (int k = t; k < nvals; k += 256) {
        int ee = k / NC, q = k - ee * NC;
        out[base + k] = ls[ee * 11 + q];
    }
}

extern "C" void kernel_launch(void* const* d_in, const int* in_sizes, int n_in,
                              void* d_out, int out_size, void* d_ws, size_t ws_size,
                              hipStream_t stream) {
    const float* x_user  = (const float*)d_in[0];
    const float* x_movie = (const float*)d_in[1];
    const int*   ei      = (const int*)d_in[2];
    const float* Wu = (const float*)d_in[3];
    const float* bu = (const float*)d_in[4];
    const float* Wm = (const float*)d_in[5];
    const float* bm = (const float*)d_in[6];
    const float* W1 = (const float*)d_in[7];
    const float* b1 = (const float*)d_in[8];
    const float* W2 = (const float*)d_in[9];
    const float* b2 = (const float*)d_in[10];
    const float* We = (const float*)d_in[11];
    const float* be = (const float*)d_in[12];
    float* out = (float*)d_out;

    int E = in_sizes[2] / 2;
    const int* row = ei;
    const int* col = ei + E;

    char* p = (char*)d_ws;
    auto alloc = [&](size_t bytes) -> void* {
        void* r = (void*)p;
        p += (bytes + 255) & ~(size_t)255;
        return r;
    };
    int*   counts  = (int*)alloc((size_t)NN * 4);
    int*   offsets = (int*)alloc((size_t)(NN + 1) * 4);
    int*   cursor  = (int*)alloc((size_t)NN * 4);
    int*   csr     = (int*)alloc((size_t)E * 4);
    float* dinv    = (float*)alloc((size_t)NN * 4);
    int*   sums    = (int*)alloc((size_t)512 * 4);
    float* WuT     = (float*)alloc((size_t)FU * HD * 4);
    float* WmT     = (float*)alloc((size_t)FM * HD * 4);
    float* W1T     = (float*)alloc((size_t)HD * HD * 4);
    float* W2T     = (float*)alloc((size_t)HD * HD * 4);
    float* P       = (float*)alloc((size_t)NN * NC * 4);
    float* buf0    = (float*)alloc((size_t)NN * HD * 4);
    float* buf1    = (float*)alloc((size_t)NN * HD * 4);

    const int tb = 256;
    const int nscan = (NN + 255) / 256;  // 391

    hipMemsetAsync(counts, 0, (size_t)NN * 4, stream);
    k_count<<<(E + tb - 1) / tb, tb, 0, stream>>>(col, E, counts);
    k_scanA<<<nscan, 256, 0, stream>>>(counts, sums);
    k_scanB<<<1, 512, 0, stream>>>(sums, nscan, offsets);
    k_scanC<<<nscan, 256, 0, stream>>>(counts, sums, offsets, cursor, dinv);
    k_fill<<<(E + tb - 1) / tb, tb, 0, stream>>>(row, col, E, cursor, csr);

    k_transpose4<<<176, 256, 0, stream>>>(Wu, Wm, W1, W2, WuT, WmT, W1T, W2T);

    // embed: user rows (K=32) then movie rows (K=64) into buf0
    k_gemm<FU, false, false><<<(NU + 63) / 64, 256, 0, stream>>>(x_user, WuT, bu, nullptr, buf0, NU);
    k_gemm<FM, false, false><<<(NM + 63) / 64, 256, 0, stream>>>(x_movie, WmT, bm, nullptr,
                                                                 buf0 + (size_t)NU * HD, NM);

    // layer 1: h' = dinv * (x @ W1^T + b1); agg
    k_gemm<HD, false, true><<<(NN + 63) / 64, 256, 0, stream>>>(buf0, W1T, b1, dinv, buf1, NN);
    k_agg<false><<<NN / 4, 256, 0, stream>>>(buf1, offsets, csr, dinv, buf0, nullptr, nullptr, nullptr);

    // layer 2: h' = dinv * (relu(agg1) @ W2^T + b2); agg + fused projection
    k_gemm<HD, true, true><<<(NN + 63) / 64, 256, 0, stream>>>(buf0, W2T, b2, dinv, buf1, NN);
    k_agg<true><<<NN / 4, 256, 0, stream>>>(buf1, offsets, csr, dinv, nullptr, We, be, P);

    k_edge_out<<<(E + tb - 1) / tb, tb, 0, stream>>>(row, col, P, out, E);
}

// Round 4
// 463.062 us; speedup vs baseline: 2.6242x; 1.2200x over previous
//
#include <hip/hip_runtime.h>
#include <hip/hip_fp16.h>

#define NU 50000
#define NM 50000
#define NN 100000
#define FU 32
#define FM 64
#define HD 128
#define NC 10

// ============ CSR build (user nodes only — edges never touch movies) ============

__global__ void k_count(const int* __restrict__ col, int E, int* __restrict__ counts) {
    int e = blockIdx.x * blockDim.x + threadIdx.x;
    if (e < E) atomicAdd(&counts[col[e]], 1);
}

__device__ inline int wave_incl_scan(int x, int l) {
#pragma unroll
    for (int d = 1; d < 64; d <<= 1) {
        int u = __shfl_up(x, d, 64);
        if (l >= d) x += u;
    }
    return x;
}

template <int NWAVE>
__device__ inline int block_excl_scan(int v, int t, int* wsum, int* out_total) {
    int l = t & 63, w = t >> 6;
    int inc = wave_incl_scan(v, l);
    if (l == 63) wsum[w] = inc;
    __syncthreads();
    int base = 0;
    int tot = 0;
#pragma unroll
    for (int i = 0; i < NWAVE; i++) {
        int s = wsum[i];
        if (i < w) base += s;
        tot += s;
    }
    if (out_total) *out_total = tot;
    return base + inc - v;
}

__global__ void k_scanA(const int* __restrict__ counts, int* __restrict__ sums) {
    __shared__ int wsum[4];
    int t = threadIdx.x;
    int idx = blockIdx.x * 256 + t;
    int v = (idx < NU) ? counts[idx] : 0;
    int total;
    block_excl_scan<4>(v, t, wsum, &total);
    if (t == 0) sums[blockIdx.x] = total;
}

__global__ void k_scanB(int* __restrict__ sums, int nblk, int* __restrict__ offsets) {
    __shared__ int wsum[4];
    int t = threadIdx.x;  // 256
    int v = (t < nblk) ? sums[t] : 0;
    int total;
    int excl = block_excl_scan<4>(v, t, wsum, &total);
    if (t < nblk) sums[t] = excl;
    if (t == 0) offsets[NU] = total;
}

__global__ void k_scanC(const int* __restrict__ counts, const int* __restrict__ sums,
                        int* __restrict__ offsets, int* __restrict__ cursor,
                        float* __restrict__ dinv) {
    __shared__ int wsum[4];
    int t = threadIdx.x;
    int idx = blockIdx.x * 256 + t;
    int v = (idx < NU) ? counts[idx] : 0;
    int excl = block_excl_scan<4>(v, t, wsum, nullptr);
    if (idx < NU) {
        int off = sums[blockIdx.x] + excl;
        offsets[idx] = off;
        cursor[idx] = off;
        dinv[idx] = rsqrtf((float)(v + 1));
    }
}

__global__ void k_fill(const int* __restrict__ row, const int* __restrict__ col, int E,
                       int* __restrict__ cursor, int* __restrict__ csr_src) {
    int e = blockIdx.x * blockDim.x + threadIdx.x;
    if (e < E) {
        int c = col[e];
        int pos = atomicAdd(&cursor[c], 1);
        csr_src[pos] = row[e];
    }
}

// ============ weight folding: WcU = W1*Wu (as [32][128] transposed), WcM = W1*Wm,
//              W2T transpose, bcU = W1*bu + b1, bcM = W1*bm + b1 ============

__global__ void k_fold(const float* __restrict__ Wu, const float* __restrict__ bu,
                       const float* __restrict__ Wm, const float* __restrict__ bm,
                       const float* __restrict__ W1, const float* __restrict__ b1,
                       const float* __restrict__ W2,
                       float* __restrict__ WcUT, float* __restrict__ bcU,
                       float* __restrict__ WcMT, float* __restrict__ bcM,
                       float* __restrict__ W2T) {
    int bid = blockIdx.x, t = threadIdx.x;
    if (bid < 16) {                       // WcUT[k][c], k<32, c<128
        int f = bid * 256 + t;
        int k = f >> 7, c = f & 127;
        float s = 0.f;
        for (int j = 0; j < 128; j++) s += W1[c * 128 + j] * Wu[j * 32 + k];
        WcUT[f] = s;
    } else if (bid < 48) {                // WcMT[k][c], k<64
        int f = (bid - 16) * 256 + t;
        int k = f >> 7, c = f & 127;
        float s = 0.f;
        for (int j = 0; j < 128; j++) s += W1[c * 128 + j] * Wm[j * 64 + k];
        WcMT[f] = s;
    } else if (bid < 112) {               // W2T[k][c] = W2[c][k]
        int f = (bid - 48) * 256 + t;
        int k = f >> 7, c = f & 127;
        W2T[f] = W2[c * 128 + k];
    } else {
        if (t < 128) {
            float s = 0.f;
            for (int j = 0; j < 128; j++) s += W1[t * 128 + j] * bu[j];
            bcU[t] = s + b1[t];
        } else if (t < 256) {
            int c = t - 128;
            float s = 0.f;
            for (int j = 0; j < 128; j++) s += W1[c * 128 + j] * bm[j];
            bcM[c] = s + b1[c];
        }
    }
}

// ============ fp16 PRE-SCALED user features: xs16[n] = dinv[n] * x_user[n] ============
// (layer-1 gather table; the dinv_r weight lives in the table — this was the round-3 bug)

__global__ void k_half(const float* __restrict__ x, const float* __restrict__ dinv,
                       __half2* __restrict__ o, int n2) {
    int i = blockIdx.x * 256 + threadIdx.x;
    if (i < n2) {
        float2 v = ((const float2*)x)[i];
        float s = dinv[i >> 4];   // 16 half2 per node
        o[i] = __floats2half2_rn(v.x * s, v.y * s);
    }
}

// ============ layer-1 aggregation in raw 32-dim feature space ============
// gfull[c] = dinv[c]^2 * x_u[c] + dinv[c] * sum_r dinv[r]*x_u[r]   (table pre-scaled)
// beta[c]  = dinv[c]^2 + dinv[c] * sum_r dinv[r]
__global__ void k_agg1(const __half2* __restrict__ xs16, const float* __restrict__ x_user,
                       const int* __restrict__ offsets, const int* __restrict__ csr,
                       const float* __restrict__ dinv,
                       float* __restrict__ gfull, float* __restrict__ beta) {
    int t = threadIdx.x;
    int l = t & 63, w = t >> 6;
    int n = blockIdx.x * 4 + w;
    int sub = l >> 4, fp = l & 15;   // 4 subgroups x 16 half2-features
    int s = offsets[n], e = offsets[n + 1];
    float2 acc = make_float2(0.f, 0.f);
    float sacc = 0.f;
    int j = s + sub;
    for (; j + 4 < e; j += 8) {
        int r0 = csr[j], r1 = csr[j + 4];
        float2 a = __half22float2(xs16[r0 * 16 + fp]);
        float2 b = __half22float2(xs16[r1 * 16 + fp]);
        acc.x += a.x + b.x;
        acc.y += a.y + b.y;
        if (fp == 0) sacc += dinv[r0] + dinv[r1];
    }
    if (j < e) {
        int r0 = csr[j];
        float2 a = __half22float2(xs16[r0 * 16 + fp]);
        acc.x += a.x; acc.y += a.y;
        if (fp == 0) sacc += dinv[r0];
    }
    // reduce across the 4 subgroups
    acc.x += __shfl_xor(acc.x, 16, 64); acc.y += __shfl_xor(acc.y, 16, 64);
    acc.x += __shfl_xor(acc.x, 32, 64); acc.y += __shfl_xor(acc.y, 32, 64);
    sacc += __shfl_xor(sacc, 16, 64);
    sacc += __shfl_xor(sacc, 32, 64);
    float dn = dinv[n];
    if (l < 16) {
        float2 xv = ((const float2*)x_user)[n * 16 + l];
        float2 o;
        o.x = dn * dn * xv.x + dn * acc.x;
        o.y = dn * dn * xv.y + dn * acc.y;
        ((float2*)gfull)[n * 16 + l] = o;
    }
    if (l == 0) beta[n] = dn * dn + dn * sacc;
}

// ============ GEMM mainloop over an LDS x-tile (64 rows x K) ============

template <int K>
__device__ inline void gemm_ldsx(const float* xs, const float4* __restrict__ Wt4,
                                 int cg, int m0, float acc[8][4]) {
#pragma unroll 2
    for (int k4 = 0; k4 < K / 4; k4++) {
        int kb = k4 * 4;
        float4 w0 = Wt4[(kb + 0) * 32 + cg];
        float4 w1 = Wt4[(kb + 1) * 32 + cg];
        float4 w2 = Wt4[(kb + 2) * 32 + cg];
        float4 w3 = Wt4[(kb + 3) * 32 + cg];
#pragma unroll
        for (int m = 0; m < 8; m++) {
            float4 xf = *(const float4*)&xs[(m0 + m) * K + kb];
            acc[m][0] += xf.x * w0.x + xf.y * w1.x + xf.z * w2.x + xf.w * w3.x;
            acc[m][1] += xf.x * w0.y + xf.y * w1.y + xf.z * w2.y + xf.w * w3.y;
            acc[m][2] += xf.x * w0.z + xf.y * w1.z + xf.z * w2.z + xf.w * w3.z;
            acc[m][3] += xf.x * w0.w + xf.y * w1.w + xf.z * w2.w + xf.w * w3.w;
        }
    }
}

// ============ fused user chain: (gfull @ WcUT + beta*bcU) -> relu -> @W2T + b2, *dinv -> fp16
__global__ void k_user(const float* __restrict__ gfull, const float* __restrict__ beta,
                       const float* __restrict__ WcUT, const float* __restrict__ bcU,
                       const float* __restrict__ W2T, const float* __restrict__ b2,
                       const float* __restrict__ dinv, __half2* __restrict__ h2p) {
    __shared__ float xs[64 * 32];
    __shared__ float ys[64 * 128];
    int t = threadIdx.x;
    int n0 = blockIdx.x * 64;
    const float4* xv = (const float4*)gfull;
    float4* xsv = (float4*)xs;
#pragma unroll
    for (int i = t; i < 512; i += 256) {
        int r = i >> 3;
        int n = n0 + r;
        float4 v = make_float4(0.f, 0.f, 0.f, 0.f);
        if (n < NU) v = xv[n * 8 + (i & 7)];
        xsv[i] = v;
    }
    __syncthreads();
    int cg = t & 31, m0 = (t >> 5) * 8;
    float acc[8][4];
    float4 bv = ((const float4*)bcU)[cg];
#pragma unroll
    for (int m = 0; m < 8; m++) {
        int n = n0 + m0 + m;
        float be_ = (n < NU) ? beta[n] : 0.f;
        acc[m][0] = be_ * bv.x; acc[m][1] = be_ * bv.y;
        acc[m][2] = be_ * bv.z; acc[m][3] = be_ * bv.w;
    }
    gemm_ldsx<32>(xs, (const float4*)WcUT, cg, m0, acc);
#pragma unroll
    for (int m = 0; m < 8; m++) {
        float4 o = make_float4(fmaxf(acc[m][0], 0.f), fmaxf(acc[m][1], 0.f),
                               fmaxf(acc[m][2], 0.f), fmaxf(acc[m][3], 0.f));
        *(float4*)&ys[(m0 + m) * 128 + cg * 4] = o;
    }
    __syncthreads();
    float4 bv2 = ((const float4*)b2)[cg];
#pragma unroll
    for (int m = 0; m < 8; m++) {
        acc[m][0] = bv2.x; acc[m][1] = bv2.y; acc[m][2] = bv2.z; acc[m][3] = bv2.w;
    }
    gemm_ldsx<128>(ys, (const float4*)W2T, cg, m0, acc);
#pragma unroll
    for (int m = 0; m < 8; m++) {
        int n = n0 + m0 + m;
        if (n < NU) {
            float s = dinv[n];
            h2p[n * 64 + cg * 2]     = __floats2half2_rn(acc[m][0] * s, acc[m][1] * s);
            h2p[n * 64 + cg * 2 + 1] = __floats2half2_rn(acc[m][2] * s, acc[m][3] * s);
        }
    }
}

// ============ fused movie chain: (x_movie @ WcMT + bcM) -> relu -> @W2T + b2 -> fp32
__global__ void k_movie(const float* __restrict__ xm,
                        const float* __restrict__ WcMT, const float* __restrict__ bcM,
                        const float* __restrict__ W2T, const float* __restrict__ b2,
                        float* __restrict__ h2m) {
    __shared__ float xs[64 * 64];
    __shared__ float ys[64 * 128];
    int t = threadIdx.x;
    int n0 = blockIdx.x * 64;
    const float4* xv = (const float4*)xm;
    float4* xsv = (float4*)xs;
#pragma unroll
    for (int i = t; i < 1024; i += 256) {
        int r = i >> 4;
        int n = n0 + r;
        float4 v = make_float4(0.f, 0.f, 0.f, 0.f);
        if (n < NM) v = xv[n * 16 + (i & 15)];
        xsv[i] = v;
    }
    __syncthreads();
    int cg = t & 31, m0 = (t >> 5) * 8;
    float acc[8][4];
    float4 bv = ((const float4*)bcM)[cg];
#pragma unroll
    for (int m = 0; m < 8; m++) {
        acc[m][0] = bv.x; acc[m][1] = bv.y; acc[m][2] = bv.z; acc[m][3] = bv.w;
    }
    gemm_ldsx<64>(xs, (const float4*)WcMT, cg, m0, acc);
#pragma unroll
    for (int m = 0; m < 8; m++) {
        float4 o = make_float4(fmaxf(acc[m][0], 0.f), fmaxf(acc[m][1], 0.f),
                               fmaxf(acc[m][2], 0.f), fmaxf(acc[m][3], 0.f));
        *(float4*)&ys[(m0 + m) * 128 + cg * 4] = o;
    }
    __syncthreads();
    float4 bv2 = ((const float4*)b2)[cg];
#pragma unroll
    for (int m = 0; m < 8; m++) {
        acc[m][0] = bv2.x; acc[m][1] = bv2.y; acc[m][2] = bv2.z; acc[m][3] = bv2.w;
    }
    gemm_ldsx<128>(ys, (const float4*)W2T, cg, m0, acc);
#pragma unroll
    for (int m = 0; m < 8; m++) {
        int n = n0 + m0 + m;
        if (n < NM) {
            *(float4*)&h2m[(size_t)n * 128 + cg * 4] =
                make_float4(acc[m][0], acc[m][1], acc[m][2], acc[m][3]);
        }
    }
}

// ============ layer-2 aggregation (fp16 pre-scaled table) + fused projection -> P_u (with be)
__global__ void k_agg2(const __half2* __restrict__ hv, const int* __restrict__ offsets,
                       const int* __restrict__ csr, const float* __restrict__ dinv,
                       const float* __restrict__ We, const float* __restrict__ be,
                       float* __restrict__ P) {
    int t = threadIdx.x;
    int l = t & 63, w = t >> 6;
    int n = blockIdx.x * 4 + w;
    float2 acc = __half22float2(hv[n * 64 + l]);
    int s = offsets[n], e = offsets[n + 1];
    int j = s;
    for (; j + 4 <= e; j += 4) {
        int r0 = csr[j], r1 = csr[j + 1], r2 = csr[j + 2], r3 = csr[j + 3];
        float2 a = __half22float2(hv[r0 * 64 + l]);
        float2 b = __half22float2(hv[r1 * 64 + l]);
        float2 c = __half22float2(hv[r2 * 64 + l]);
        float2 d = __half22float2(hv[r3 * 64 + l]);
        acc.x += a.x + b.x + c.x + d.x;
        acc.y += a.y + b.y + c.y + d.y;
    }
    for (; j < e; j++) {
        int r = csr[j];
        float2 v = __half22float2(hv[r * 64 + l]);
        acc.x += v.x; acc.y += v.y;
    }
    float dn = dinv[n];
    float v0 = fmaxf(acc.x * dn, 0.f);
    float v1 = fmaxf(acc.y * dn, 0.f);
    float p[NC];
#pragma unroll
    for (int q = 0; q < NC; q++) {
        float2 wv = *(const float2*)&We[q * 256 + 2 * l];
        p[q] = wv.x * v0 + wv.y * v1;
    }
#pragma unroll
    for (int q = 0; q < NC; q++) {
#pragma unroll
        for (int d = 32; d >= 1; d >>= 1) p[q] += __shfl_xor(p[q], d, 64);
    }
    if (l == 0) {
#pragma unroll
        for (int q = 0; q < NC; q++) P[n * NC + q] = p[q] + be[q];
    }
}

// ============ movie projection: P_m = We_m . relu(h2m)  (no be) ============
__global__ void k_mproj(const float* __restrict__ h2m, const float* __restrict__ We,
                        float* __restrict__ P) {
    int t = threadIdx.x;
    int l = t & 63, w = t >> 6;
    int n = blockIdx.x * 4 + w;   // movie-local index
    float2 xv = ((const float2*)h2m)[n * 64 + l];
    float v0 = fmaxf(xv.x, 0.f);
    float v1 = fmaxf(xv.y, 0.f);
    float p[NC];
#pragma unroll
    for (int q = 0; q < NC; q++) {
        float2 wv = *(const float2*)&We[q * 256 + 128 + 2 * l];
        p[q] = wv.x * v0 + wv.y * v1;
    }
#pragma unroll
    for (int q = 0; q < NC; q++) {
#pragma unroll
        for (int d = 32; d >= 1; d >>= 1) p[q] += __shfl_xor(p[q], d, 64);
    }
    if (l == 0) {
#pragma unroll
        for (int q = 0; q < NC; q++) P[(NU + n) * NC + q] = p[q];
    }
}

// ============ edge output: out[e] = P[row[e]] + P[NU + col[e]] ============
__global__ void k_edge_out(const int* __restrict__ row, const int* __restrict__ col,
                           const float* __restrict__ P, float* __restrict__ out, int E) {
    __shared__ float ls[256 * 11];
    int t = threadIdx.x;
    int e0 = blockIdx.x * 256;
    int e = e0 + t;
    if (e < E) {
        int r = row[e], c = col[e];
        const float2* pu = (const float2*)(P + (size_t)r * NC);
        const float2* pm = (const float2*)(P + (size_t)(NU + c) * NC);
#pragma unroll
        for (int q = 0; q < 5; q++) {
            float2 a = pu[q], b = pm[q];
            ls[t * 11 + 2 * q] = a.x + b.x;
            ls[t * 11 + 2 * q + 1] = a.y + b.y;
        }
    }
    __syncthreads();
    int nvals = (E - e0 < 256 ? E - e0 : 256) * NC;
    size_t base = (size_t)e0 * NC;
    for (int k = t; k < nvals; k += 256) {
        int ee = k / NC, q = k - ee * NC;
        out[base + k] = ls[ee * 11 + q];
    }
}

extern "C" void kernel_launch(void* const* d_in, const int* in_sizes, int n_in,
                              void* d_out, int out_size, void* d_ws, size_t ws_size,
                              hipStream_t stream) {
    const float* x_user  = (const float*)d_in[0];
    const float* x_movie = (const float*)d_in[1];
    const int*   ei      = (const int*)d_in[2];
    const float* Wu = (const float*)d_in[3];
    const float* bu = (const float*)d_in[4];
    const float* Wm = (const float*)d_in[5];
    const float* bm = (const float*)d_in[6];
    const float* W1 = (const float*)d_in[7];
    const float* b1 = (const float*)d_in[8];
    const float* W2 = (const float*)d_in[9];
    const float* b2 = (const float*)d_in[10];
    const float* We = (const float*)d_in[11];
    const float* be = (const float*)d_in[12];
    float* out = (float*)d_out;

    int E = in_sizes[2] / 2;
    const int* row = ei;
    const int* col = ei + E;

    char* p = (char*)d_ws;
    auto alloc = [&](size_t bytes) -> void* {
        void* r = (void*)p;
        p += (bytes + 255) & ~(size_t)255;
        return r;
    };
    int*     counts  = (int*)alloc((size_t)NU * 4);
    int*     offsets = (int*)alloc((size_t)(NU + 1) * 4);
    int*     cursor  = (int*)alloc((size_t)NU * 4);
    int*     csr     = (int*)alloc((size_t)E * 4);
    float*   dinv    = (float*)alloc((size_t)NU * 4);
    float*   beta    = (float*)alloc((size_t)NU * 4);
    int*     sums    = (int*)alloc((size_t)256 * 4);
    float*   WcUT    = (float*)alloc((size_t)FU * HD * 4);
    float*   WcMT    = (float*)alloc((size_t)FM * HD * 4);
    float*   W2T     = (float*)alloc((size_t)HD * HD * 4);
    float*   bcU     = (float*)alloc((size_t)HD * 4);
    float*   bcM     = (float*)alloc((size_t)HD * 4);
    __half2* xs16    = (__half2*)alloc((size_t)NU * FU * 2);
    float*   gfull   = (float*)alloc((size_t)NU * FU * 4);
    __half2* h2p     = (__half2*)alloc((size_t)NU * HD * 2);
    float*   h2m     = (float*)alloc((size_t)NM * HD * 4);
    float*   P       = (float*)alloc((size_t)NN * NC * 4);

    const int tb = 256;
    const int nscan = (NU + 255) / 256;  // 196

    hipMemsetAsync(counts, 0, (size_t)NU * 4, stream);
    k_count<<<(E + tb - 1) / tb, tb, 0, stream>>>(col, E, counts);
    k_scanA<<<nscan, 256, 0, stream>>>(counts, sums);
    k_scanB<<<1, 256, 0, stream>>>(sums, nscan, offsets);
    k_scanC<<<nscan, 256, 0, stream>>>(counts, sums, offsets, cursor, dinv);
    k_fill<<<(E + tb - 1) / tb, tb, 0, stream>>>(row, col, E, cursor, csr);

    k_fold<<<113, 256, 0, stream>>>(Wu, bu, Wm, bm, W1, b1, W2, WcUT, bcU, WcMT, bcM, W2T);
    // pre-scaled fp16 table (needs dinv -> after k_scanC)
    k_half<<<(NU * FU / 2 + 255) / 256, 256, 0, stream>>>(x_user, dinv, xs16, NU * FU / 2);

    k_agg1<<<NU / 4, 256, 0, stream>>>(xs16, x_user, offsets, csr, dinv, gfull, beta);

    k_user<<<(NU + 63) / 64, 256, 0, stream>>>(gfull, beta, WcUT, bcU, W2T, b2, dinv, h2p);
    k_movie<<<(NM + 63) / 64, 256, 0, stream>>>(x_movie, WcMT, bcM, W2T, b2, h2m);

    k_agg2<<<NU / 4, 256, 0, stream>>>(h2p, offsets, csr, dinv, We, be, P);
    k_mproj<<<NM / 4, 256, 0, stream>>>(h2m, We, P);

    k_edge_out<<<(E + tb - 1) / tb, tb, 0, stream>>>(row, col, P, out, E);
}

// Round 5
// 378.986 us; speedup vs baseline: 3.2063x; 1.2218x over previous
//
#include <hip/hip_runtime.h>
#include <hip/hip_fp16.h>

#define NU 50000
#define NM 50000
#define NN 100000
#define FU 32
#define FM 64
#define HD 128
#define NC 10

#define NB 196      // buckets of 256 destination cols
#define CAP 8192    // per-bucket staging capacity (mean 5102, +43 sigma)
#define CHUNK 4096  // edges per k_bucket block

// ============ scan helpers ============

__device__ inline int wave_incl_scan(int x, int l) {
#pragma unroll
    for (int d = 1; d < 64; d <<= 1) {
        int u = __shfl_up(x, d, 64);
        if (l >= d) x += u;
    }
    return x;
}

template <int NWAVE>
__device__ inline int block_excl_scan(int v, int t, int* wsum, int* out_total) {
    int l = t & 63, w = t >> 6;
    int inc = wave_incl_scan(v, l);
    if (l == 63) wsum[w] = inc;
    __syncthreads();
    int base = 0;
    int tot = 0;
#pragma unroll
    for (int i = 0; i < NWAVE; i++) {
        int s = wsum[i];
        if (i < w) base += s;
        tot += s;
    }
    if (out_total) *out_total = tot;
    return base + inc - v;
}

// ============ bucketed CSR build ============
// pairs[b*CAP + i] = row | (col<<16), grouped by bucket b = col>>8

__global__ void k_bucket(const int* __restrict__ row, const int* __restrict__ col, int E,
                         int* __restrict__ bucket_cur, unsigned int* __restrict__ pairs) {
    __shared__ int hist[NB];
    __shared__ int lofs[NB];
    __shared__ int gbase[NB];
    __shared__ int lcur[NB];
    __shared__ int wsum[4];
    __shared__ unsigned int stage[CHUNK];
    int t = threadIdx.x;
    int e0 = blockIdx.x * CHUNK;
    int cnt = min(CHUNK, E - e0);
    for (int i = t; i < NB; i += 256) hist[i] = 0;
    __syncthreads();
    unsigned int pk[CHUNK / 256];
#pragma unroll
    for (int i = 0; i < CHUNK / 256; i++) {
        int k = i * 256 + t;
        if (k < cnt) {
            unsigned int r = (unsigned int)row[e0 + k];
            unsigned int c = (unsigned int)col[e0 + k];
            pk[i] = r | (c << 16);
            atomicAdd(&hist[c >> 8], 1);
        }
    }
    __syncthreads();
    int v = (t < NB) ? hist[t] : 0;
    int excl = block_excl_scan<4>(v, t, wsum, nullptr);
    if (t < NB) {
        lofs[t] = excl;
        lcur[t] = excl;
        gbase[t] = atomicAdd(&bucket_cur[t], v);
    }
    __syncthreads();
#pragma unroll
    for (int i = 0; i < CHUNK / 256; i++) {
        int k = i * 256 + t;
        if (k < cnt) {
            int pos = atomicAdd(&lcur[pk[i] >> 24], 1);  // (c>>8) == pk>>24
            stage[pos] = pk[i];
        }
    }
    __syncthreads();
    int w = t >> 6, l = t & 63;
    for (int b = w; b < NB; b += 4) {
        int start = lofs[b], n = hist[b];
        unsigned int g = (unsigned int)b * CAP + (unsigned int)gbase[b];
        for (int i = l; i < n; i += 64) pairs[g + i] = stage[start + i];
    }
}

// per-col degree counts from bucketed pairs (one block per bucket)
__global__ void k_bcount(const unsigned int* __restrict__ pairs,
                         const int* __restrict__ bucket_cur, int* __restrict__ counts) {
    __shared__ int lc[256];
    int b = blockIdx.x, t = threadIdx.x;
    lc[t] = 0;
    __syncthreads();
    int n = bucket_cur[b];
    unsigned int base = (unsigned int)b * CAP;
    for (int i = t; i < n; i += 256) {
        unsigned int c = pairs[base + i] >> 16;
        atomicAdd(&lc[c & 255], 1);
    }
    __syncthreads();
    int col0 = b << 8;
    if (col0 + t < NU) counts[col0 + t] = lc[t];
}

__global__ void k_scanA(const int* __restrict__ counts, int* __restrict__ sums) {
    __shared__ int wsum[4];
    int t = threadIdx.x;
    int idx = blockIdx.x * 256 + t;
    int v = (idx < NU) ? counts[idx] : 0;
    int total;
    block_excl_scan<4>(v, t, wsum, &total);
    if (t == 0) sums[blockIdx.x] = total;
}

__global__ void k_scanB(int* __restrict__ sums, int nblk, int* __restrict__ offsets) {
    __shared__ int wsum[4];
    int t = threadIdx.x;  // 256
    int v = (t < nblk) ? sums[t] : 0;
    int total;
    int excl = block_excl_scan<4>(v, t, wsum, &total);
    if (t < nblk) sums[t] = excl;
    if (t == 0) offsets[NU] = total;
}

__global__ void k_scanC(const int* __restrict__ counts, const int* __restrict__ sums,
                        int* __restrict__ offsets, float* __restrict__ dinv) {
    __shared__ int wsum[4];
    int t = threadIdx.x;
    int idx = blockIdx.x * 256 + t;
    int v = (idx < NU) ? counts[idx] : 0;
    int excl = block_excl_scan<4>(v, t, wsum, nullptr);
    if (idx < NU) {
        offsets[idx] = sums[blockIdx.x] + excl;
        dinv[idx] = rsqrtf((float)(v + 1));
    }
}

// scatter within bucket window (one block per bucket); csr stored as u16
__global__ void k_scatter(const unsigned int* __restrict__ pairs,
                          const int* __restrict__ bucket_cur, const int* __restrict__ offsets,
                          unsigned short* __restrict__ csr16) {
    __shared__ int lcur[256];
    int b = blockIdx.x, t = threadIdx.x;
    int col0 = b << 8;
    lcur[t] = (col0 + t < NU) ? offsets[col0 + t] : 0;
    __syncthreads();
    int n = bucket_cur[b];
    unsigned int base = (unsigned int)b * CAP;
    for (int i = t; i < n; i += 256) {
        unsigned int pk = pairs[base + i];
        int pos = atomicAdd(&lcur[(pk >> 16) & 255], 1);
        csr16[pos] = (unsigned short)(pk & 0xffffu);
    }
}

// ============ weight folding: WcU = W1*Wu (as [32][128] transposed), WcM = W1*Wm,
//              W2T transpose, bcU = W1*bu + b1, bcM = W1*bm + b1 ============

__global__ void k_fold(const float* __restrict__ Wu, const float* __restrict__ bu,
                       const float* __restrict__ Wm, const float* __restrict__ bm,
                       const float* __restrict__ W1, const float* __restrict__ b1,
                       const float* __restrict__ W2,
                       float* __restrict__ WcUT, float* __restrict__ bcU,
                       float* __restrict__ WcMT, float* __restrict__ bcM,
                       float* __restrict__ W2T) {
    int bid = blockIdx.x, t = threadIdx.x;
    if (bid < 16) {                       // WcUT[k][c], k<32, c<128
        int f = bid * 256 + t;
        int k = f >> 7, c = f & 127;
        float s = 0.f;
        for (int j = 0; j < 128; j++) s += W1[c * 128 + j] * Wu[j * 32 + k];
        WcUT[f] = s;
    } else if (bid < 48) {                // WcMT[k][c], k<64
        int f = (bid - 16) * 256 + t;
        int k = f >> 7, c = f & 127;
        float s = 0.f;
        for (int j = 0; j < 128; j++) s += W1[c * 128 + j] * Wm[j * 64 + k];
        WcMT[f] = s;
    } else if (bid < 112) {               // W2T[k][c] = W2[c][k]
        int f = (bid - 48) * 256 + t;
        int k = f >> 7, c = f & 127;
        W2T[f] = W2[c * 128 + k];
    } else {
        if (t < 128) {
            float s = 0.f;
            for (int j = 0; j < 128; j++) s += W1[t * 128 + j] * bu[j];
            bcU[t] = s + b1[t];
        } else if (t < 256) {
            int c = t - 128;
            float s = 0.f;
            for (int j = 0; j < 128; j++) s += W1[c * 128 + j] * bm[j];
            bcM[c] = s + b1[c];
        }
    }
}

// ============ fp16 PRE-SCALED user features: xs16[n] = dinv[n] * x_user[n] ============

__global__ void k_half(const float* __restrict__ x, const float* __restrict__ dinv,
                       __half2* __restrict__ o, int n2) {
    int i = blockIdx.x * 256 + threadIdx.x;
    if (i < n2) {
        float2 v = ((const float2*)x)[i];
        float s = dinv[i >> 4];   // 16 half2 per node
        o[i] = __floats2half2_rn(v.x * s, v.y * s);
    }
}

// ============ layer-1 aggregation in raw 32-dim feature space ============
// gfull[c] = dinv[c]^2 * x_u[c] + dinv[c] * sum_r dinv[r]*x_u[r]   (table pre-scaled)
// beta[c]  = dinv[c]^2 + dinv[c] * sum_r dinv[r]
__global__ void k_agg1(const __half2* __restrict__ xs16, const float* __restrict__ x_user,
                       const int* __restrict__ offsets, const unsigned short* __restrict__ csr,
                       const float* __restrict__ dinv,
                       float* __restrict__ gfull, float* __restrict__ beta) {
    int t = threadIdx.x;
    int l = t & 63, w = t >> 6;
    int n = blockIdx.x * 4 + w;
    int sub = l >> 4, fp = l & 15;   // 4 subgroups x 16 half2-features
    int s = offsets[n], e = offsets[n + 1];
    float2 acc = make_float2(0.f, 0.f);
    float sacc = 0.f;
    int j = s + sub;
    for (; j + 4 < e; j += 8) {
        int r0 = csr[j], r1 = csr[j + 4];
        float2 a = __half22float2(xs16[r0 * 16 + fp]);
        float2 b = __half22float2(xs16[r1 * 16 + fp]);
        acc.x += a.x + b.x;
        acc.y += a.y + b.y;
        if (fp == 0) sacc += dinv[r0] + dinv[r1];
    }
    if (j < e) {
        int r0 = csr[j];
        float2 a = __half22float2(xs16[r0 * 16 + fp]);
        acc.x += a.x; acc.y += a.y;
        if (fp == 0) sacc += dinv[r0];
    }
    acc.x += __shfl_xor(acc.x, 16, 64); acc.y += __shfl_xor(acc.y, 16, 64);
    acc.x += __shfl_xor(acc.x, 32, 64); acc.y += __shfl_xor(acc.y, 32, 64);
    sacc += __shfl_xor(sacc, 16, 64);
    sacc += __shfl_xor(sacc, 32, 64);
    float dn = dinv[n];
    if (l < 16) {
        float2 xv = ((const float2*)x_user)[n * 16 + l];
        float2 o;
        o.x = dn * dn * xv.x + dn * acc.x;
        o.y = dn * dn * xv.y + dn * acc.y;
        ((float2*)gfull)[n * 16 + l] = o;
    }
    if (l == 0) beta[n] = dn * dn + dn * sacc;
}

// ============ GEMM mainloop over an LDS x-tile (64 rows x K) ============

template <int K>
__device__ inline void gemm_ldsx(const float* xs, const float4* __restrict__ Wt4,
                                 int cg, int m0, float acc[8][4]) {
#pragma unroll 2
    for (int k4 = 0; k4 < K / 4; k4++) {
        int kb = k4 * 4;
        float4 w0 = Wt4[(kb + 0) * 32 + cg];
        float4 w1 = Wt4[(kb + 1) * 32 + cg];
        float4 w2 = Wt4[(kb + 2) * 32 + cg];
        float4 w3 = Wt4[(kb + 3) * 32 + cg];
#pragma unroll
        for (int m = 0; m < 8; m++) {
            float4 xf = *(const float4*)&xs[(m0 + m) * K + kb];
            acc[m][0] += xf.x * w0.x + xf.y * w1.x + xf.z * w2.x + xf.w * w3.x;
            acc[m][1] += xf.x * w0.y + xf.y * w1.y + xf.z * w2.y + xf.w * w3.y;
            acc[m][2] += xf.x * w0.z + xf.y * w1.z + xf.z * w2.z + xf.w * w3.z;
            acc[m][3] += xf.x * w0.w + xf.y * w1.w + xf.z * w2.w + xf.w * w3.w;
        }
    }
}

// ============ fused user chain: (gfull @ WcUT + beta*bcU) -> relu -> @W2T + b2, *dinv -> fp16
__global__ void k_user(const float* __restrict__ gfull, const float* __restrict__ beta,
                       const float* __restrict__ WcUT, const float* __restrict__ bcU,
                       const float* __restrict__ W2T, const float* __restrict__ b2,
                       const float* __restrict__ dinv, __half2* __restrict__ h2p) {
    __shared__ float xs[64 * 32];
    __shared__ float ys[64 * 128];
    int t = threadIdx.x;
    int n0 = blockIdx.x * 64;
    const float4* xv = (const float4*)gfull;
    float4* xsv = (float4*)xs;
#pragma unroll
    for (int i = t; i < 512; i += 256) {
        int r = i >> 3;
        int n = n0 + r;
        float4 v = make_float4(0.f, 0.f, 0.f, 0.f);
        if (n < NU) v = xv[n * 8 + (i & 7)];
        xsv[i] = v;
    }
    __syncthreads();
    int cg = t & 31, m0 = (t >> 5) * 8;
    float acc[8][4];
    float4 bv = ((const float4*)bcU)[cg];
#pragma unroll
    for (int m = 0; m < 8; m++) {
        int n = n0 + m0 + m;
        float be_ = (n < NU) ? beta[n] : 0.f;
        acc[m][0] = be_ * bv.x; acc[m][1] = be_ * bv.y;
        acc[m][2] = be_ * bv.z; acc[m][3] = be_ * bv.w;
    }
    gemm_ldsx<32>(xs, (const float4*)WcUT, cg, m0, acc);
#pragma unroll
    for (int m = 0; m < 8; m++) {
        float4 o = make_float4(fmaxf(acc[m][0], 0.f), fmaxf(acc[m][1], 0.f),
                               fmaxf(acc[m][2], 0.f), fmaxf(acc[m][3], 0.f));
        *(float4*)&ys[(m0 + m) * 128 + cg * 4] = o;
    }
    __syncthreads();
    float4 bv2 = ((const float4*)b2)[cg];
#pragma unroll
    for (int m = 0; m < 8; m++) {
        acc[m][0] = bv2.x; acc[m][1] = bv2.y; acc[m][2] = bv2.z; acc[m][3] = bv2.w;
    }
    gemm_ldsx<128>(ys, (const float4*)W2T, cg, m0, acc);
#pragma unroll
    for (int m = 0; m < 8; m++) {
        int n = n0 + m0 + m;
        if (n < NU) {
            float s = dinv[n];
            h2p[n * 64 + cg * 2]     = __floats2half2_rn(acc[m][0] * s, acc[m][1] * s);
            h2p[n * 64 + cg * 2 + 1] = __floats2half2_rn(acc[m][2] * s, acc[m][3] * s);
        }
    }
}

// ============ fused movie chain: (x_movie @ WcMT + bcM) -> relu -> @W2T + b2 -> fp32
__global__ void k_movie(const float* __restrict__ xm,
                        const float* __restrict__ WcMT, const float* __restrict__ bcM,
                        const float* __restrict__ W2T, const float* __restrict__ b2,
                        float* __restrict__ h2m) {
    __shared__ float xs[64 * 64];
    __shared__ float ys[64 * 128];
    int t = threadIdx.x;
    int n0 = blockIdx.x * 64;
    const float4* xv = (const float4*)xm;
    float4* xsv = (float4*)xs;
#pragma unroll
    for (int i = t; i < 1024; i += 256) {
        int r = i >> 4;
        int n = n0 + r;
        float4 v = make_float4(0.f, 0.f, 0.f, 0.f);
        if (n < NM) v = xv[n * 16 + (i & 15)];
        xsv[i] = v;
    }
    __syncthreads();
    int cg = t & 31, m0 = (t >> 5) * 8;
    float acc[8][4];
    float4 bv = ((const float4*)bcM)[cg];
#pragma unroll
    for (int m = 0; m < 8; m++) {
        acc[m][0] = bv.x; acc[m][1] = bv.y; acc[m][2] = bv.z; acc[m][3] = bv.w;
    }
    gemm_ldsx<64>(xs, (const float4*)WcMT, cg, m0, acc);
#pragma unroll
    for (int m = 0; m < 8; m++) {
        float4 o = make_float4(fmaxf(acc[m][0], 0.f), fmaxf(acc[m][1], 0.f),
                               fmaxf(acc[m][2], 0.f), fmaxf(acc[m][3], 0.f));
        *(float4*)&ys[(m0 + m) * 128 + cg * 4] = o;
    }
    __syncthreads();
    float4 bv2 = ((const float4*)b2)[cg];
#pragma unroll
    for (int m = 0; m < 8; m++) {
        acc[m][0] = bv2.x; acc[m][1] = bv2.y; acc[m][2] = bv2.z; acc[m][3] = bv2.w;
    }
    gemm_ldsx<128>(ys, (const float4*)W2T, cg, m0, acc);
#pragma unroll
    for (int m = 0; m < 8; m++) {
        int n = n0 + m0 + m;
        if (n < NM) {
            *(float4*)&h2m[(size_t)n * 128 + cg * 4] =
                make_float4(acc[m][0], acc[m][1], acc[m][2], acc[m][3]);
        }
    }
}

// ============ layer-2 aggregation (fp16 pre-scaled table) + fused projection -> P_u (with be)
__global__ void k_agg2(const __half2* __restrict__ hv, const int* __restrict__ offsets,
                       const unsigned short* __restrict__ csr, const float* __restrict__ dinv,
                       const float* __restrict__ We, const float* __restrict__ be,
                       float* __restrict__ P) {
    int t = threadIdx.x;
    int l = t & 63, w = t >> 6;
    int n = blockIdx.x * 4 + w;
    float2 acc = __half22float2(hv[n * 64 + l]);
    int s = offsets[n], e = offsets[n + 1];
    int j = s;
    for (; j + 4 <= e; j += 4) {
        int r0 = csr[j], r1 = csr[j + 1], r2 = csr[j + 2], r3 = csr[j + 3];
        float2 a = __half22float2(hv[r0 * 64 + l]);
        float2 b = __half22float2(hv[r1 * 64 + l]);
        float2 c = __half22float2(hv[r2 * 64 + l]);
        float2 d = __half22float2(hv[r3 * 64 + l]);
        acc.x += a.x + b.x + c.x + d.x;
        acc.y += a.y + b.y + c.y + d.y;
    }
    for (; j < e; j++) {
        int r = csr[j];
        float2 v = __half22float2(hv[r * 64 + l]);
        acc.x += v.x; acc.y += v.y;
    }
    float dn = dinv[n];
    float v0 = fmaxf(acc.x * dn, 0.f);
    float v1 = fmaxf(acc.y * dn, 0.f);
    float p[NC];
#pragma unroll
    for (int q = 0; q < NC; q++) {
        float2 wv = *(const float2*)&We[q * 256 + 2 * l];
        p[q] = wv.x * v0 + wv.y * v1;
    }
#pragma unroll
    for (int q = 0; q < NC; q++) {
#pragma unroll
        for (int d = 32; d >= 1; d >>= 1) p[q] += __shfl_xor(p[q], d, 64);
    }
    if (l == 0) {
#pragma unroll
        for (int q = 0; q < NC; q++) P[n * NC + q] = p[q] + be[q];
    }
}

// ============ movie projection: P_m = We_m . relu(h2m)  (no be) ============
__global__ void k_mproj(const float* __restrict__ h2m, const float* __restrict__ We,
                        float* __restrict__ P) {
    int t = threadIdx.x;
    int l = t & 63, w = t >> 6;
    int n = blockIdx.x * 4 + w;   // movie-local index
    float2 xv = ((const float2*)h2m)[n * 64 + l];
    float v0 = fmaxf(xv.x, 0.f);
    float v1 = fmaxf(xv.y, 0.f);
    float p[NC];
#pragma unroll
    for (int q = 0; q < NC; q++) {
        float2 wv = *(const float2*)&We[q * 256 + 128 + 2 * l];
        p[q] = wv.x * v0 + wv.y * v1;
    }
#pragma unroll
    for (int q = 0; q < NC; q++) {
#pragma unroll
        for (int d = 32; d >= 1; d >>= 1) p[q] += __shfl_xor(p[q], d, 64);
    }
    if (l == 0) {
#pragma unroll
        for (int q = 0; q < NC; q++) P[(NU + n) * NC + q] = p[q];
    }
}

// ============ edge output: out[e] = P[row[e]] + P[NU + col[e]] ============
__global__ void k_edge_out(const int* __restrict__ row, const int* __restrict__ col,
                           const float* __restrict__ P, float* __restrict__ out, int E) {
    __shared__ float ls[256 * 11];
    int t = threadIdx.x;
    int e0 = blockIdx.x * 256;
    int e = e0 + t;
    if (e < E) {
        int r = row[e], c = col[e];
        const float2* pu = (const float2*)(P + (size_t)r * NC);
        const float2* pm = (const float2*)(P + (size_t)(NU + c) * NC);
#pragma unroll
        for (int q = 0; q < 5; q++) {
            float2 a = pu[q], b = pm[q];
            ls[t * 11 + 2 * q] = a.x + b.x;
            ls[t * 11 + 2 * q + 1] = a.y + b.y;
        }
    }
    __syncthreads();
    int nvals = (E - e0 < 256 ? E - e0 : 256) * NC;
    size_t base = (size_t)e0 * NC;
    for (int k = t; k < nvals; k += 256) {
        int ee = k / NC, q = k - ee * NC;
        out[base + k] = ls[ee * 11 + q];
    }
}

extern "C" void kernel_launch(void* const* d_in, const int* in_sizes, int n_in,
                              void* d_out, int out_size, void* d_ws, size_t ws_size,
                              hipStream_t stream) {
    const float* x_user  = (const float*)d_in[0];
    const float* x_movie = (const float*)d_in[1];
    const int*   ei      = (const int*)d_in[2];
    const float* Wu = (const float*)d_in[3];
    const float* bu = (const float*)d_in[4];
    const float* Wm = (const float*)d_in[5];
    const float* bm = (const float*)d_in[6];
    const float* W1 = (const float*)d_in[7];
    const float* b1 = (const float*)d_in[8];
    const float* W2 = (const float*)d_in[9];
    const float* b2 = (const float*)d_in[10];
    const float* We = (const float*)d_in[11];
    const float* be = (const float*)d_in[12];
    float* out = (float*)d_out;

    int E = in_sizes[2] / 2;
    const int* row = ei;
    const int* col = ei + E;

    char* p = (char*)d_ws;
    auto alloc = [&](size_t bytes) -> void* {
        void* r = (void*)p;
        p += (bytes + 255) & ~(size_t)255;
        return r;
    };
    int*            counts     = (int*)alloc((size_t)NU * 4);
    int*            offsets    = (int*)alloc((size_t)(NU + 1) * 4);
    unsigned short* csr16      = (unsigned short*)alloc((size_t)E * 2);
    unsigned int*   pairs      = (unsigned int*)alloc((size_t)NB * CAP * 4);
    int*            bucket_cur = (int*)alloc((size_t)NB * 4);
    float*          dinv       = (float*)alloc((size_t)NU * 4);
    float*          beta       = (float*)alloc((size_t)NU * 4);
    int*            sums       = (int*)alloc((size_t)256 * 4);
    float*          WcUT       = (float*)alloc((size_t)FU * HD * 4);
    float*          WcMT       = (float*)alloc((size_t)FM * HD * 4);
    float*          W2T        = (float*)alloc((size_t)HD * HD * 4);
    float*          bcU        = (float*)alloc((size_t)HD * 4);
    float*          bcM        = (float*)alloc((size_t)HD * 4);
    __half2*        xs16       = (__half2*)alloc((size_t)NU * FU * 2);
    float*          gfull      = (float*)alloc((size_t)NU * FU * 4);
    __half2*        h2p        = (__half2*)alloc((size_t)NU * HD * 2);
    float*          h2m        = (float*)alloc((size_t)NM * HD * 4);
    float*          P          = (float*)alloc((size_t)NN * NC * 4);

    const int tb = 256;
    const int nscan = (NU + 255) / 256;  // 196

    hipMemsetAsync(bucket_cur, 0, (size_t)NB * 4, stream);
    k_bucket<<<(E + CHUNK - 1) / CHUNK, 256, 0, stream>>>(row, col, E, bucket_cur, pairs);
    k_bcount<<<NB, 256, 0, stream>>>(pairs, bucket_cur, counts);
    k_scanA<<<nscan, 256, 0, stream>>>(counts, sums);
    k_scanB<<<1, 256, 0, stream>>>(sums, nscan, offsets);
    k_scanC<<<nscan, 256, 0, stream>>>(counts, sums, offsets, dinv);
    k_scatter<<<NB, 256, 0, stream>>>(pairs, bucket_cur, offsets, csr16);

    k_fold<<<113, 256, 0, stream>>>(Wu, bu, Wm, bm, W1, b1, W2, WcUT, bcU, WcMT, bcM, W2T);
    k_half<<<(NU * FU / 2 + 255) / 256, 256, 0, stream>>>(x_user, dinv, xs16, NU * FU / 2);

    k_agg1<<<NU / 4, 256, 0, stream>>>(xs16, x_user, offsets, csr16, dinv, gfull, beta);

    k_user<<<(NU + 63) / 64, 256, 0, stream>>>(gfull, beta, WcUT, bcU, W2T, b2, dinv, h2p);
    k_movie<<<(NM + 63) / 64, 256, 0, stream>>>(x_movie, WcMT, bcM, W2T, b2, h2m);

    k_agg2<<<NU / 4, 256, 0, stream>>>(h2p, offsets, csr16, dinv, We, be, P);
    k_mproj<<<NM / 4, 256, 0, stream>>>(h2m, We, P);

    k_edge_out<<<(E + tb - 1) / tb, tb, 0, stream>>>(row, col, P, out, E);
}

// Round 6
// 318.267 us; speedup vs baseline: 3.8180x; 1.1908x over previous
//
#include <hip/hip_runtime.h>
#include <hip/hip_fp16.h>

#define NU 50000
#define NM 50000
#define NN 100000
#define FU 32
#define FM 64
#define HD 128
#define NC 10

#define NB 196      // buckets of 256 destination cols
#define CAP 8192    // per-bucket staging capacity (mean 5102, +43 sigma)
#define CHUNK 4096  // edges per k_bucket block

typedef __attribute__((ext_vector_type(8))) _Float16 half8;
typedef __attribute__((ext_vector_type(4))) float f32x4;

// ============ scan helpers ============

__device__ inline int wave_incl_scan(int x, int l) {
#pragma unroll
    for (int d = 1; d < 64; d <<= 1) {
        int u = __shfl_up(x, d, 64);
        if (l >= d) x += u;
    }
    return x;
}

template <int NWAVE>
__device__ inline int block_excl_scan(int v, int t, int* wsum, int* out_total) {
    int l = t & 63, w = t >> 6;
    int inc = wave_incl_scan(v, l);
    if (l == 63) wsum[w] = inc;
    __syncthreads();
    int base = 0;
    int tot = 0;
#pragma unroll
    for (int i = 0; i < NWAVE; i++) {
        int s = wsum[i];
        if (i < w) base += s;
        tot += s;
    }
    if (out_total) *out_total = tot;
    return base + inc - v;
}

// ============ bucketed CSR build ============
// pairs[b*CAP + i] = row | (col<<16), grouped by bucket b = col>>8

__global__ void k_bucket(const int* __restrict__ row, const int* __restrict__ col, int E,
                         int* __restrict__ bucket_cur, unsigned int* __restrict__ pairs) {
    __shared__ int hist[NB];
    __shared__ int lofs[NB];
    __shared__ int gbase[NB];
    __shared__ int lcur[NB];
    __shared__ int wsum[4];
    __shared__ unsigned int stage[CHUNK];
    int t = threadIdx.x;
    int e0 = blockIdx.x * CHUNK;
    int cnt = min(CHUNK, E - e0);
    for (int i = t; i < NB; i += 256) hist[i] = 0;
    __syncthreads();
    unsigned int pk[CHUNK / 256];
#pragma unroll
    for (int i = 0; i < CHUNK / 256; i++) {
        int k = i * 256 + t;
        if (k < cnt) {
            unsigned int r = (unsigned int)row[e0 + k];
            unsigned int c = (unsigned int)col[e0 + k];
            pk[i] = r | (c << 16);
            atomicAdd(&hist[c >> 8], 1);
        }
    }
    __syncthreads();
    int v = (t < NB) ? hist[t] : 0;
    int excl = block_excl_scan<4>(v, t, wsum, nullptr);
    if (t < NB) {
        lofs[t] = excl;
        lcur[t] = excl;
        gbase[t] = atomicAdd(&bucket_cur[t], v);
    }
    __syncthreads();
#pragma unroll
    for (int i = 0; i < CHUNK / 256; i++) {
        int k = i * 256 + t;
        if (k < cnt) {
            int pos = atomicAdd(&lcur[pk[i] >> 24], 1);  // (c>>8) == pk>>24
            stage[pos] = pk[i];
        }
    }
    __syncthreads();
    int w = t >> 6, l = t & 63;
    for (int b = w; b < NB; b += 4) {
        int start = lofs[b], n = hist[b];
        unsigned int g = (unsigned int)b * CAP + (unsigned int)gbase[b];
        for (int i = l; i < n; i += 64) pairs[g + i] = stage[start + i];
    }
}

// per-col degree counts from bucketed pairs (one block per bucket)
__global__ void k_bcount(const unsigned int* __restrict__ pairs,
                         const int* __restrict__ bucket_cur, int* __restrict__ counts) {
    __shared__ int lc[256];
    int b = blockIdx.x, t = threadIdx.x;
    lc[t] = 0;
    __syncthreads();
    int n = bucket_cur[b];
    unsigned int base = (unsigned int)b * CAP;
    for (int i = t; i < n; i += 256) {
        unsigned int c = pairs[base + i] >> 16;
        atomicAdd(&lc[c & 255], 1);
    }
    __syncthreads();
    int col0 = b << 8;
    if (col0 + t < NU) counts[col0 + t] = lc[t];
}

__global__ void k_scanA(const int* __restrict__ counts, int* __restrict__ sums) {
    __shared__ int wsum[4];
    int t = threadIdx.x;
    int idx = blockIdx.x * 256 + t;
    int v = (idx < NU) ? counts[idx] : 0;
    int total;
    block_excl_scan<4>(v, t, wsum, &total);
    if (t == 0) sums[blockIdx.x] = total;
}

__global__ void k_scanB(int* __restrict__ sums, int nblk, int* __restrict__ offsets) {
    __shared__ int wsum[4];
    int t = threadIdx.x;  // 256
    int v = (t < nblk) ? sums[t] : 0;
    int total;
    int excl = block_excl_scan<4>(v, t, wsum, &total);
    if (t < nblk) sums[t] = excl;
    if (t == 0) offsets[NU] = total;
}

__global__ void k_scanC(const int* __restrict__ counts, const int* __restrict__ sums,
                        int* __restrict__ offsets, float* __restrict__ dinv) {
    __shared__ int wsum[4];
    int t = threadIdx.x;
    int idx = blockIdx.x * 256 + t;
    int v = (idx < NU) ? counts[idx] : 0;
    int excl = block_excl_scan<4>(v, t, wsum, nullptr);
    if (idx < NU) {
        offsets[idx] = sums[blockIdx.x] + excl;
        dinv[idx] = rsqrtf((float)(v + 1));
    }
}

// scatter within bucket window (one block per bucket); csr stored as u16
__global__ void k_scatter(const unsigned int* __restrict__ pairs,
                          const int* __restrict__ bucket_cur, const int* __restrict__ offsets,
                          unsigned short* __restrict__ csr16) {
    __shared__ int lcur[256];
    int b = blockIdx.x, t = threadIdx.x;
    int col0 = b << 8;
    lcur[t] = (col0 + t < NU) ? offsets[col0 + t] : 0;
    __syncthreads();
    int n = bucket_cur[b];
    unsigned int base = (unsigned int)b * CAP;
    for (int i = t; i < n; i += 256) {
        unsigned int pk = pairs[base + i];
        int pos = atomicAdd(&lcur[(pk >> 16) & 255], 1);
        csr16[pos] = (unsigned short)(pk & 0xffffu);
    }
}

// ============ weight folding: WcU = W1*Wu (as [32][128] transposed), WcM = W1*Wm,
//              W2T transpose, bcU = W1*bu + b1, bcM = W1*bm + b1 ============

__global__ void k_fold(const float* __restrict__ Wu, const float* __restrict__ bu,
                       const float* __restrict__ Wm, const float* __restrict__ bm,
                       const float* __restrict__ W1, const float* __restrict__ b1,
                       const float* __restrict__ W2,
                       float* __restrict__ WcUT, float* __restrict__ bcU,
                       float* __restrict__ WcMT, float* __restrict__ bcM,
                       float* __restrict__ W2T) {
    int bid = blockIdx.x, t = threadIdx.x;
    if (bid < 16) {                       // WcUT[k][c], k<32, c<128
        int f = bid * 256 + t;
        int k = f >> 7, c = f & 127;
        float s = 0.f;
        for (int j = 0; j < 128; j++) s += W1[c * 128 + j] * Wu[j * 32 + k];
        WcUT[f] = s;
    } else if (bid < 48) {                // WcMT[k][c], k<64
        int f = (bid - 16) * 256 + t;
        int k = f >> 7, c = f & 127;
        float s = 0.f;
        for (int j = 0; j < 128; j++) s += W1[c * 128 + j] * Wm[j * 64 + k];
        WcMT[f] = s;
    } else if (bid < 112) {               // W2T[k][c] = W2[c][k]
        int f = (bid - 48) * 256 + t;
        int k = f >> 7, c = f & 127;
        W2T[f] = W2[c * 128 + k];
    } else {
        if (t < 128) {
            float s = 0.f;
            for (int j = 0; j < 128; j++) s += W1[t * 128 + j] * bu[j];
            bcU[t] = s + b1[t];
        } else if (t < 256) {
            int c = t - 128;
            float s = 0.f;
            for (int j = 0; j < 128; j++) s += W1[c * 128 + j] * bm[j];
            bcM[c] = s + b1[c];
        }
    }
}

// ============ MFMA B-fragment tables (fp16, lane-ordered) ============
// v_mfma_f32_16x16x32_f16: A[m=lane&15][k=(lane>>4)*8+j]; B[k=(lane>>4)*8+j][n=lane&15]
// fragWcU: [t8][l][j]       (K=32,  1 k-step)   512 groups
// fragWcM: [t8][s][l][j]    (K=64,  2 k-steps) 1024 groups
// fragW2:  [t8][s][l][j]    (K=128, 4 k-steps) 2048 groups
__global__ void k_wfrag(const float* __restrict__ WcUT, const float* __restrict__ WcMT,
                        const float* __restrict__ W2T,
                        _Float16* __restrict__ fragWcU, _Float16* __restrict__ fragWcM,
                        _Float16* __restrict__ fragW2) {
    int g = blockIdx.x * 256 + threadIdx.x;
    if (g >= 3584) return;
    half8 out;
    _Float16* dst;
    if (g < 512) {
        int t8 = g >> 6, l = g & 63;
#pragma unroll
        for (int j = 0; j < 8; j++)
            out[j] = (_Float16)WcUT[((l >> 4) * 8 + j) * 128 + t8 * 16 + (l & 15)];
        dst = &fragWcU[g * 8];
    } else if (g < 1536) {
        int g2 = g - 512;
        int t8 = g2 >> 7, s = (g2 >> 6) & 1, l = g2 & 63;
#pragma unroll
        for (int j = 0; j < 8; j++)
            out[j] = (_Float16)WcMT[(s * 32 + (l >> 4) * 8 + j) * 128 + t8 * 16 + (l & 15)];
        dst = &fragWcM[g2 * 8];
    } else {
        int g2 = g - 1536;
        int t8 = g2 >> 8, s = (g2 >> 6) & 3, l = g2 & 63;
#pragma unroll
        for (int j = 0; j < 8; j++)
            out[j] = (_Float16)W2T[(s * 32 + (l >> 4) * 8 + j) * 128 + t8 * 16 + (l & 15)];
        dst = &fragW2[g2 * 8];
    }
    *(half8*)dst = out;
}

// ============ fp16 PRE-SCALED user features: xs16[n] = dinv[n] * x_user[n] ============

__global__ void k_half(const float* __restrict__ x, const float* __restrict__ dinv,
                       __half2* __restrict__ o, int n2) {
    int i = blockIdx.x * 256 + threadIdx.x;
    if (i < n2) {
        float2 v = ((const float2*)x)[i];
        float s = dinv[i >> 4];   // 16 half2 per node
        o[i] = __floats2half2_rn(v.x * s, v.y * s);
    }
}

// ============ layer-1 aggregation in raw 32-dim feature space ============
// gfull[c] = dinv[c]^2 * x_u[c] + dinv[c] * sum_r dinv[r]*x_u[r]   (table pre-scaled)
// beta[c]  = dinv[c]^2 + dinv[c] * sum_r dinv[r]
__global__ void k_agg1(const __half2* __restrict__ xs16, const float* __restrict__ x_user,
                       const int* __restrict__ offsets, const unsigned short* __restrict__ csr,
                       const float* __restrict__ dinv,
                       float* __restrict__ gfull, float* __restrict__ beta) {
    int t = threadIdx.x;
    int l = t & 63, w = t >> 6;
    int n = blockIdx.x * 4 + w;
    int sub = l >> 4, fp = l & 15;   // 4 subgroups x 16 half2-features
    int s = offsets[n], e = offsets[n + 1];
    float2 acc = make_float2(0.f, 0.f);
    float sacc = 0.f;
    int j = s + sub;
    for (; j + 4 < e; j += 8) {
        int r0 = csr[j], r1 = csr[j + 4];
        float2 a = __half22float2(xs16[r0 * 16 + fp]);
        float2 b = __half22float2(xs16[r1 * 16 + fp]);
        acc.x += a.x + b.x;
        acc.y += a.y + b.y;
        if (fp == 0) sacc += dinv[r0] + dinv[r1];
    }
    if (j < e) {
        int r0 = csr[j];
        float2 a = __half22float2(xs16[r0 * 16 + fp]);
        acc.x += a.x; acc.y += a.y;
        if (fp == 0) sacc += dinv[r0];
    }
    acc.x += __shfl_xor(acc.x, 16, 64); acc.y += __shfl_xor(acc.y, 16, 64);
    acc.x += __shfl_xor(acc.x, 32, 64); acc.y += __shfl_xor(acc.y, 32, 64);
    sacc += __shfl_xor(sacc, 16, 64);
    sacc += __shfl_xor(sacc, 32, 64);
    float dn = dinv[n];
    if (l < 16) {
        float2 xv = ((const float2*)x_user)[n * 16 + l];
        float2 o;
        o.x = dn * dn * xv.x + dn * acc.x;
        o.y = dn * dn * xv.y + dn * acc.y;
        ((float2*)gfull)[n * 16 + l] = o;
    }
    if (l == 0) beta[n] = dn * dn + dn * sacc;
}

// ============ fused user chain (MFMA): (gfull @ WcU + beta*bcU) -> relu -> @W2 + b2, *dinv -> fp16
__global__ void __launch_bounds__(256) k_user(
        const float* __restrict__ gfull, const float* __restrict__ beta,
        const _Float16* __restrict__ fragWcU, const float* __restrict__ bcU,
        const _Float16* __restrict__ fragW2, const float* __restrict__ b2,
        const float* __restrict__ dinv, _Float16* __restrict__ h2p) {
    __shared__ _Float16 xs[64 * 40];   // 64 rows x K=32 (pad 40)
    __shared__ _Float16 ys[64 * 136];  // 64 rows x 128 (pad 136)
    int t = threadIdx.x;
    int n0 = blockIdx.x * 64;
    {   // stage gfull -> xs fp16 (wave-local rows)
        int r = t >> 2, c0 = (t & 3) * 8;
        int n = n0 + r;
        float4 a = make_float4(0.f, 0.f, 0.f, 0.f), b = a;
        if (n < NU) {
            const float4* g4 = (const float4*)gfull;
            a = g4[n * 8 + (c0 >> 2)];
            b = g4[n * 8 + (c0 >> 2) + 1];
        }
        half8 h;
        h[0] = (_Float16)a.x; h[1] = (_Float16)a.y; h[2] = (_Float16)a.z; h[3] = (_Float16)a.w;
        h[4] = (_Float16)b.x; h[5] = (_Float16)b.y; h[6] = (_Float16)b.z; h[7] = (_Float16)b.w;
        *(half8*)&xs[r * 40 + c0] = h;
    }
    __syncthreads();
    int l = t & 63, w = t >> 6;
    int lr = l & 15, lq = l >> 4;
    // GEMM1: K=32, one mfma step per n-tile
    half8 af = *(half8*)&xs[(16 * w + lr) * 40 + lq * 8];
    const half8* fU = (const half8*)fragWcU;
    f32x4 zero = {0.f, 0.f, 0.f, 0.f};
    f32x4 acc[8];
#pragma unroll
    for (int t8 = 0; t8 < 8; t8++) {
        half8 bf = fU[t8 * 64 + l];
        acc[t8] = __builtin_amdgcn_mfma_f32_16x16x32_f16(af, bf, zero, 0, 0, 0);
    }
    float betav[4];
#pragma unroll
    for (int r = 0; r < 4; r++) {
        int n = n0 + 16 * w + lq * 4 + r;
        betav[r] = (n < NU) ? beta[n] : 0.f;
    }
#pragma unroll
    for (int t8 = 0; t8 < 8; t8++) {
        float bc = bcU[16 * t8 + lr];
#pragma unroll
        for (int r = 0; r < 4; r++) {
            float v = fmaxf(acc[t8][r] + betav[r] * bc, 0.f);
            ys[(16 * w + lq * 4 + r) * 136 + 16 * t8 + lr] = (_Float16)v;
        }
    }
    __syncthreads();
    // GEMM2: K=128, 4 mfma steps
    f32x4 acc2[8];
#pragma unroll
    for (int t8 = 0; t8 < 8; t8++) acc2[t8] = zero;
    const half8* fW = (const half8*)fragW2;
#pragma unroll
    for (int s = 0; s < 4; s++) {
        half8 a2 = *(half8*)&ys[(16 * w + lr) * 136 + s * 32 + lq * 8];
#pragma unroll
        for (int t8 = 0; t8 < 8; t8++) {
            half8 bf = fW[(t8 * 4 + s) * 64 + l];
            acc2[t8] = __builtin_amdgcn_mfma_f32_16x16x32_f16(a2, bf, acc2[t8], 0, 0, 0);
        }
    }
#pragma unroll
    for (int r = 0; r < 4; r++) {
        int n = n0 + 16 * w + lq * 4 + r;
        if (n < NU) {
            float s = dinv[n];
#pragma unroll
            for (int t8 = 0; t8 < 8; t8++) {
                int c = 16 * t8 + lr;
                h2p[n * 128 + c] = (_Float16)((acc2[t8][r] + b2[c]) * s);
            }
        }
    }
}

// ============ fused movie chain (MFMA): (x_movie @ WcM + bcM) -> relu -> @W2 + b2 -> fp32
__global__ void __launch_bounds__(256) k_movie(
        const float* __restrict__ xm,
        const _Float16* __restrict__ fragWcM, const float* __restrict__ bcM,
        const _Float16* __restrict__ fragW2, const float* __restrict__ b2,
        float* __restrict__ h2m) {
    __shared__ _Float16 xs[64 * 72];   // 64 rows x K=64 (pad 72)
    __shared__ _Float16 ys[64 * 136];
    int t = threadIdx.x;
    int n0 = blockIdx.x * 64;
    {   // stage x_movie -> xs fp16
        int r = t >> 2, c0 = (t & 3) * 16;
        int n = n0 + r;
        float4 a = make_float4(0.f, 0.f, 0.f, 0.f), b = a, c = a, d = a;
        if (n < NM) {
            const float4* g4 = (const float4*)xm;
            a = g4[n * 16 + (c0 >> 2)];
            b = g4[n * 16 + (c0 >> 2) + 1];
            c = g4[n * 16 + (c0 >> 2) + 2];
            d = g4[n * 16 + (c0 >> 2) + 3];
        }
        half8 h0, h1;
        h0[0] = (_Float16)a.x; h0[1] = (_Float16)a.y; h0[2] = (_Float16)a.z; h0[3] = (_Float16)a.w;
        h0[4] = (_Float16)b.x; h0[5] = (_Float16)b.y; h0[6] = (_Float16)b.z; h0[7] = (_Float16)b.w;
        h1[0] = (_Float16)c.x; h1[1] = (_Float16)c.y; h1[2] = (_Float16)c.z; h1[3] = (_Float16)c.w;
        h1[4] = (_Float16)d.x; h1[5] = (_Float16)d.y; h1[6] = (_Float16)d.z; h1[7] = (_Float16)d.w;
        *(half8*)&xs[r * 72 + c0] = h0;
        *(half8*)&xs[r * 72 + c0 + 8] = h1;
    }
    __syncthreads();
    int l = t & 63, w = t >> 6;
    int lr = l & 15, lq = l >> 4;
    const half8* fM = (const half8*)fragWcM;
    f32x4 zero = {0.f, 0.f, 0.f, 0.f};
    f32x4 acc[8];
#pragma unroll
    for (int t8 = 0; t8 < 8; t8++) acc[t8] = zero;
#pragma unroll
    for (int s = 0; s < 2; s++) {
        half8 af = *(half8*)&xs[(16 * w + lr) * 72 + s * 32 + lq * 8];
#pragma unroll
        for (int t8 = 0; t8 < 8; t8++) {
            half8 bf = fM[(t8 * 2 + s) * 64 + l];
            acc[t8] = __builtin_amdgcn_mfma_f32_16x16x32_f16(af, bf, acc[t8], 0, 0, 0);
        }
    }
#pragma unroll
    for (int t8 = 0; t8 < 8; t8++) {
        float bc = bcM[16 * t8 + lr];
#pragma unroll
        for (int r = 0; r < 4; r++) {
            float v = fmaxf(acc[t8][r] + bc, 0.f);
            ys[(16 * w + lq * 4 + r) * 136 + 16 * t8 + lr] = (_Float16)v;
        }
    }
    __syncthreads();
    f32x4 acc2[8];
#pragma unroll
    for (int t8 = 0; t8 < 8; t8++) acc2[t8] = zero;
    const half8* fW = (const half8*)fragW2;
#pragma unroll
    for (int s = 0; s < 4; s++) {
        half8 a2 = *(half8*)&ys[(16 * w + lr) * 136 + s * 32 + lq * 8];
#pragma unroll
        for (int t8 = 0; t8 < 8; t8++) {
            half8 bf = fW[(t8 * 4 + s) * 64 + l];
            acc2[t8] = __builtin_amdgcn_mfma_f32_16x16x32_f16(a2, bf, acc2[t8], 0, 0, 0);
        }
    }
#pragma unroll
    for (int r = 0; r < 4; r++) {
        int n = n0 + 16 * w + lq * 4 + r;
        if (n < NM) {
#pragma unroll
            for (int t8 = 0; t8 < 8; t8++) {
                int c = 16 * t8 + lr;
                h2m[(size_t)n * 128 + c] = acc2[t8][r] + b2[c];
            }
        }
    }
}

// ============ layer-2 aggregation (fp16 pre-scaled table) + fused projection -> P_u (with be)
__global__ void k_agg2(const __half2* __restrict__ hv, const int* __restrict__ offsets,
                       const unsigned short* __restrict__ csr, const float* __restrict__ dinv,
                       const float* __restrict__ We, const float* __restrict__ be,
                       float* __restrict__ P) {
    int t = threadIdx.x;
    int l = t & 63, w = t >> 6;
    int n = blockIdx.x * 4 + w;
    float2 acc = __half22float2(hv[n * 64 + l]);
    int s = offsets[n], e = offsets[n + 1];
    int j = s;
    for (; j + 4 <= e; j += 4) {
        int r0 = csr[j], r1 = csr[j + 1], r2 = csr[j + 2], r3 = csr[j + 3];
        float2 a = __half22float2(hv[r0 * 64 + l]);
        float2 b = __half22float2(hv[r1 * 64 + l]);
        float2 c = __half22float2(hv[r2 * 64 + l]);
        float2 d = __half22float2(hv[r3 * 64 + l]);
        acc.x += a.x + b.x + c.x + d.x;
        acc.y += a.y + b.y + c.y + d.y;
    }
    for (; j < e; j++) {
        int r = csr[j];
        float2 v = __half22float2(hv[r * 64 + l]);
        acc.x += v.x; acc.y += v.y;
    }
    float dn = dinv[n];
    float v0 = fmaxf(acc.x * dn, 0.f);
    float v1 = fmaxf(acc.y * dn, 0.f);
    float p[NC];
#pragma unroll
    for (int q = 0; q < NC; q++) {
        float2 wv = *(const float2*)&We[q * 256 + 2 * l];
        p[q] = wv.x * v0 + wv.y * v1;
    }
#pragma unroll
    for (int q = 0; q < NC; q++) {
#pragma unroll
        for (int d = 32; d >= 1; d >>= 1) p[q] += __shfl_xor(p[q], d, 64);
    }
    if (l == 0) {
#pragma unroll
        for (int q = 0; q < NC; q++) P[n * NC + q] = p[q] + be[q];
    }
}

// ============ movie projection: P_m = We_m . relu(h2m)  (no be) ============
__global__ void k_mproj(const float* __restrict__ h2m, const float* __restrict__ We,
                        float* __restrict__ P) {
    int t = threadIdx.x;
    int l = t & 63, w = t >> 6;
    int n = blockIdx.x * 4 + w;   // movie-local index
    float2 xv = ((const float2*)h2m)[n * 64 + l];
    float v0 = fmaxf(xv.x, 0.f);
    float v1 = fmaxf(xv.y, 0.f);
    float p[NC];
#pragma unroll
    for (int q = 0; q < NC; q++) {
        float2 wv = *(const float2*)&We[q * 256 + 128 + 2 * l];
        p[q] = wv.x * v0 + wv.y * v1;
    }
#pragma unroll
    for (int q = 0; q < NC; q++) {
#pragma unroll
        for (int d = 32; d >= 1; d >>= 1) p[q] += __shfl_xor(p[q], d, 64);
    }
    if (l == 0) {
#pragma unroll
        for (int q = 0; q < NC; q++) P[(NU + n) * NC + q] = p[q];
    }
}

// ============ edge output: out[e] = P[row[e]] + P[NU + col[e]] ============
__global__ void k_edge_out(const int* __restrict__ row, const int* __restrict__ col,
                           const float* __restrict__ P, float* __restrict__ out, int E) {
    __shared__ float ls[256 * 11];
    int t = threadIdx.x;
    int e0 = blockIdx.x * 256;
    int e = e0 + t;
    if (e < E) {
        int r = row[e], c = col[e];
        const float2* pu = (const float2*)(P + (size_t)r * NC);
        const float2* pm = (const float2*)(P + (size_t)(NU + c) * NC);
#pragma unroll
        for (int q = 0; q < 5; q++) {
            float2 a = pu[q], b = pm[q];
            ls[t * 11 + 2 * q] = a.x + b.x;
            ls[t * 11 + 2 * q + 1] = a.y + b.y;
        }
    }
    __syncthreads();
    int nvals = (E - e0 < 256 ? E - e0 : 256) * NC;
    size_t base = (size_t)e0 * NC;
    for (int k = t; k < nvals; k += 256) {
        int ee = k / NC, q = k - ee * NC;
        out[base + k] = ls[ee * 11 + q];
    }
}

extern "C" void kernel_launch(void* const* d_in, const int* in_sizes, int n_in,
                              void* d_out, int out_size, void* d_ws, size_t ws_size,
                              hipStream_t stream) {
    const float* x_user  = (const float*)d_in[0];
    const float* x_movie = (const float*)d_in[1];
    const int*   ei      = (const int*)d_in[2];
    const float* Wu = (const float*)d_in[3];
    const float* bu = (const float*)d_in[4];
    const float* Wm = (const float*)d_in[5];
    const float* bm = (const float*)d_in[6];
    const float* W1 = (const float*)d_in[7];
    const float* b1 = (const float*)d_in[8];
    const float* W2 = (const float*)d_in[9];
    const float* b2 = (const float*)d_in[10];
    const float* We = (const float*)d_in[11];
    const float* be = (const float*)d_in[12];
    float* out = (float*)d_out;

    int E = in_sizes[2] / 2;
    const int* row = ei;
    const int* col = ei + E;

    char* p = (char*)d_ws;
    auto alloc = [&](size_t bytes) -> void* {
        void* r = (void*)p;
        p += (bytes + 255) & ~(size_t)255;
        return r;
    };
    int*            counts     = (int*)alloc((size_t)NU * 4);
    int*            offsets    = (int*)alloc((size_t)(NU + 1) * 4);
    unsigned short* csr16      = (unsigned short*)alloc((size_t)E * 2);
    unsigned int*   pairs      = (unsigned int*)alloc((size_t)NB * CAP * 4);
    int*            bucket_cur = (int*)alloc((size_t)NB * 4);
    float*          dinv       = (float*)alloc((size_t)NU * 4);
    float*          beta       = (float*)alloc((size_t)NU * 4);
    int*            sums       = (int*)alloc((size_t)256 * 4);
    float*          WcUT       = (float*)alloc((size_t)FU * HD * 4);
    float*          WcMT       = (float*)alloc((size_t)FM * HD * 4);
    float*          W2T        = (float*)alloc((size_t)HD * HD * 4);
    float*          bcU        = (float*)alloc((size_t)HD * 4);
    float*          bcM        = (float*)alloc((size_t)HD * 4);
    _Float16*       fragWcU    = (_Float16*)alloc((size_t)4096 * 2);
    _Float16*       fragWcM    = (_Float16*)alloc((size_t)8192 * 2);
    _Float16*       fragW2     = (_Float16*)alloc((size_t)16384 * 2);
    __half2*        xs16       = (__half2*)alloc((size_t)NU * FU * 2);
    float*          gfull      = (float*)alloc((size_t)NU * FU * 4);
    _Float16*       h2p        = (_Float16*)alloc((size_t)NU * HD * 2);
    float*          h2m        = (float*)alloc((size_t)NM * HD * 4);
    float*          P          = (float*)alloc((size_t)NN * NC * 4);

    const int tb = 256;
    const int nscan = (NU + 255) / 256;  // 196

    hipMemsetAsync(bucket_cur, 0, (size_t)NB * 4, stream);
    k_bucket<<<(E + CHUNK - 1) / CHUNK, 256, 0, stream>>>(row, col, E, bucket_cur, pairs);
    k_bcount<<<NB, 256, 0, stream>>>(pairs, bucket_cur, counts);
    k_scanA<<<nscan, 256, 0, stream>>>(counts, sums);
    k_scanB<<<1, 256, 0, stream>>>(sums, nscan, offsets);
    k_scanC<<<nscan, 256, 0, stream>>>(counts, sums, offsets, dinv);
    k_scatter<<<NB, 256, 0, stream>>>(pairs, bucket_cur, offsets, csr16);

    k_fold<<<113, 256, 0, stream>>>(Wu, bu, Wm, bm, W1, b1, W2, WcUT, bcU, WcMT, bcM, W2T);
    k_wfrag<<<14, 256, 0, stream>>>(WcUT, WcMT, W2T, fragWcU, fragWcM, fragW2);
    k_half<<<(NU * FU / 2 + 255) / 256, 256, 0, stream>>>(x_user, dinv, xs16, NU * FU / 2);

    k_agg1<<<NU / 4, 256, 0, stream>>>(xs16, x_user, offsets, csr16, dinv, gfull, beta);

    k_user<<<(NU + 63) / 64, 256, 0, stream>>>(gfull, beta, fragWcU, bcU, fragW2, b2, dinv, h2p);
    k_movie<<<(NM + 63) / 64, 256, 0, stream>>>(x_movie, fragWcM, bcM, fragW2, b2, h2m);

    k_agg2<<<NU / 4, 256, 0, stream>>>((const __half2*)h2p, offsets, csr16, dinv, We, be, P);
    k_mproj<<<NM / 4, 256, 0, stream>>>(h2m, We, P);

    k_edge_out<<<(E + tb - 1) / tb, tb, 0, stream>>>(row, col, P, out, E);
}